// Round 2
// baseline (1279.049 us; speedup 1.0000x reference)
//
#include <hip/hip_runtime.h>
#include <hip/hip_bf16.h>

// ---------------------------------------------------------------------------
// GCN forward: h1 = relu(Agg(x@W1)+b1); h2 = relu(Agg(h1@W2)+b2);
// out = mean(h2,axis=0) @ Wout + bout
// Agg(h)[i] = dinv[i] * ( sum_{e: dst=i} dinv[src_e]*h[src_e] + dinv[i]*h[i] )
// dinv[i] = rsqrt(in_deg[i] + 1)
// NOTE: harness passes integer inputs as int32 (edge_index -> const int*).
// ---------------------------------------------------------------------------

__global__ void count_k(const int* __restrict__ ei, int* __restrict__ cnt, int E, int N) {
    int e = blockIdx.x * blockDim.x + threadIdx.x;
    if (e < E) {
        unsigned d = (unsigned)ei[(size_t)E + e];
        if (d < (unsigned)N) atomicAdd(&cnt[d], 1);
    }
}

__global__ void dinv_k(const int* __restrict__ cnt, float* __restrict__ dinv, int n) {
    int i = blockIdx.x * blockDim.x + threadIdx.x;
    if (i < n) dinv[i] = rsqrtf((float)cnt[i] + 1.0f);
}

__global__ void block_sum_k(const int* __restrict__ cnt, int* __restrict__ bsum, int n) {
    __shared__ int s[256];
    int t = threadIdx.x;
    int idx = blockIdx.x * 256 + t;
    s[t] = (idx < n) ? cnt[idx] : 0;
    __syncthreads();
    for (int o = 128; o > 0; o >>= 1) {
        if (t < o) s[t] += s[t + o];
        __syncthreads();
    }
    if (t == 0) bsum[blockIdx.x] = s[0];
}

__global__ void scan_bsums_k(const int* __restrict__ bsum, int* __restrict__ bscan, int nb) {
    __shared__ int s[2][512];
    int t = threadIdx.x;
    int v = (t < nb) ? bsum[t] : 0;
    s[0][t] = v;
    __syncthreads();
    int cur = 0;
    for (int o = 1; o < 512; o <<= 1) {
        int val = s[cur][t];
        if (t >= o) val += s[cur][t - o];
        s[cur ^ 1][t] = val;
        cur ^= 1;
        __syncthreads();
    }
    if (t < nb) bscan[t] = s[cur][t] - v;  // exclusive
}

__global__ void scan_final_k(const int* __restrict__ cnt, const int* __restrict__ bscan,
                             int* __restrict__ off, int* __restrict__ cursor, int n) {
    __shared__ int s[2][256];
    int t = threadIdx.x;
    int idx = blockIdx.x * 256 + t;
    int v = (idx < n) ? cnt[idx] : 0;
    s[0][t] = v;
    __syncthreads();
    int cur = 0;
    for (int o = 1; o < 256; o <<= 1) {
        int val = s[cur][t];
        if (t >= o) val += s[cur][t - o];
        s[cur ^ 1][t] = val;
        cur ^= 1;
        __syncthreads();
    }
    int ex = s[cur][t] - v + bscan[blockIdx.x];
    if (idx < n) { off[idx] = ex; cursor[idx] = ex; }
}

__global__ void fill_k(const int* __restrict__ ei, int* __restrict__ cursor,
                       int* __restrict__ csr, int E, int N) {
    int e = blockIdx.x * blockDim.x + threadIdx.x;
    if (e < E) {
        unsigned d = (unsigned)ei[(size_t)E + e];
        unsigned s = (unsigned)ei[e];
        if (d < (unsigned)N && s < (unsigned)N) {
            int pos = atomicAdd(&cursor[d], 1);
            csr[pos] = (int)s;
        }
    }
}

// fp32 tiled GEMM: H[M,256] = X[M,K] @ W[K,256]; 64x64 tile, BK=32, 4x4/thread
__global__ __launch_bounds__(256) void gemm256_k(const float* __restrict__ X,
                                                 const float* __restrict__ W,
                                                 float* __restrict__ H, int M, int K) {
    __shared__ float As[64][33];
    __shared__ float Bs[32][64];
    int tid = threadIdx.x;
    int tx = tid & 15, ty = tid >> 4;
    int row0 = blockIdx.x * 64, col0 = blockIdx.y * 64;
    float c[4][4] = {};

    for (int kt = 0; kt < K; kt += 32) {
#pragma unroll
        for (int l = 0; l < 2; ++l) {
            int f = tid + l * 256;        // 0..511 float4 slots
            int r = f >> 3;               // 64 rows, 8 float4 per row
            int kc = (f & 7) << 2;
            float4 v = make_float4(0.f, 0.f, 0.f, 0.f);
            int gr = row0 + r;
            if (gr < M) v = *(const float4*)(X + (size_t)gr * K + kt + kc);
            As[r][kc + 0] = v.x; As[r][kc + 1] = v.y;
            As[r][kc + 2] = v.z; As[r][kc + 3] = v.w;
        }
#pragma unroll
        for (int l = 0; l < 2; ++l) {
            int f = tid + l * 256;        // 32 rows x 16 float4
            int r = f >> 4;
            int c4 = (f & 15) << 2;
            float4 w = *(const float4*)(W + (size_t)(kt + r) * 256 + col0 + c4);
            *(float4*)&Bs[r][c4] = w;
        }
        __syncthreads();
#pragma unroll
        for (int kk = 0; kk < 32; ++kk) {
            float a0 = As[ty * 4 + 0][kk];
            float a1 = As[ty * 4 + 1][kk];
            float a2 = As[ty * 4 + 2][kk];
            float a3 = As[ty * 4 + 3][kk];
            float4 b = *(const float4*)&Bs[kk][tx << 2];
            c[0][0] += a0 * b.x; c[0][1] += a0 * b.y; c[0][2] += a0 * b.z; c[0][3] += a0 * b.w;
            c[1][0] += a1 * b.x; c[1][1] += a1 * b.y; c[1][2] += a1 * b.z; c[1][3] += a1 * b.w;
            c[2][0] += a2 * b.x; c[2][1] += a2 * b.y; c[2][2] += a2 * b.z; c[2][3] += a2 * b.w;
            c[3][0] += a3 * b.x; c[3][1] += a3 * b.y; c[3][2] += a3 * b.z; c[3][3] += a3 * b.w;
        }
        __syncthreads();
    }
#pragma unroll
    for (int i = 0; i < 4; ++i) {
        int gr = row0 + ty * 4 + i;
        if (gr < M) {
            float4 v = make_float4(c[i][0], c[i][1], c[i][2], c[i][3]);
            *(float4*)(H + (size_t)gr * 256 + col0 + (tx << 2)) = v;
        }
    }
}

// One block (256 threads) per node; thread j handles feature column j.
__global__ __launch_bounds__(256) void aggregate_k(const float* __restrict__ H,
                                                   const int* __restrict__ csr,
                                                   const int* __restrict__ off,
                                                   const int* __restrict__ cnt,
                                                   const float* __restrict__ dinv,
                                                   const float* __restrict__ bias,
                                                   float* __restrict__ O, int n) {
    int i = blockIdx.x;
    int j = threadIdx.x;
    float di = dinv[i];
    float acc = di * H[(size_t)i * 256 + j];   // self-loop term (x di again below)
    int st = off[i];
    int c = cnt[i];
    for (int e = 0; e < c; ++e) {
        int s = csr[st + e];
        acc += dinv[s] * H[(size_t)s * 256 + j];
    }
    float r = di * acc + bias[j];
    O[(size_t)i * 256 + j] = fmaxf(r, 0.0f);
}

__global__ void pool_partial_k(const float* __restrict__ B, float* __restrict__ pool, int M) {
    int j = threadIdx.x;
    float acc = 0.f;
    for (int r = blockIdx.x; r < M; r += gridDim.x)
        acc += B[(size_t)r * 256 + j];
    atomicAdd(&pool[j], acc);
}

__global__ void final_k(const float* __restrict__ pool, const float* __restrict__ Wout,
                        const float* __restrict__ bout, float* __restrict__ out, float invM) {
    __shared__ float s[256];
    int t = threadIdx.x;
    s[t] = pool[t] * invM * Wout[t];
    __syncthreads();
    for (int o = 128; o > 0; o >>= 1) {
        if (t < o) s[t] += s[t + o];
        __syncthreads();
    }
    if (t == 0) out[0] = s[0] + bout[0];
}

extern "C" void kernel_launch(void* const* d_in, const int* in_sizes, int n_in,
                              void* d_out, int out_size, void* d_ws, size_t ws_size,
                              hipStream_t stream) {
    const float* x    = (const float*)d_in[0];
    const int*   ei   = (const int*)d_in[1];      // int32 per harness conversion
    const float* W1   = (const float*)d_in[2];
    const float* b1   = (const float*)d_in[3];
    const float* W2   = (const float*)d_in[4];
    const float* b2   = (const float*)d_in[5];
    const float* Wout = (const float*)d_in[6];
    const float* bout = (const float*)d_in[7];
    float* out = (float*)d_out;

    const int N = in_sizes[0] / 128;       // 100000
    const int E = in_sizes[1] / 2;         // 1600000
    const int nb = (N + 255) / 256;        // scan blocks

    // workspace carve (512B aligned)
    char* p = (char*)d_ws;
    auto carve = [&](size_t bytes) -> void* {
        void* r = (void*)p;
        p += (bytes + 511) & ~(size_t)511;
        return r;
    };
    float* A      = (float*)carve((size_t)N * 256 * 4);
    float* Bf     = (float*)carve((size_t)N * 256 * 4);
    float* dinv   = (float*)carve((size_t)N * 4);
    int*   cnt    = (int*)carve((size_t)N * 4);
    int*   off    = (int*)carve((size_t)(N + 1) * 4);
    int*   cursor = (int*)carve((size_t)N * 4);
    int*   csr    = (int*)carve((size_t)E * 4);
    int*   bsum   = (int*)carve((size_t)nb * 4);
    int*   bscan  = (int*)carve((size_t)nb * 4);
    float* pool   = (float*)carve(256 * 4);

    hipMemsetAsync(cnt, 0, (size_t)N * 4, stream);
    hipMemsetAsync(pool, 0, 256 * 4, stream);

    count_k<<<(E + 255) / 256, 256, 0, stream>>>(ei, cnt, E, N);
    dinv_k<<<(N + 255) / 256, 256, 0, stream>>>(cnt, dinv, N);
    block_sum_k<<<nb, 256, 0, stream>>>(cnt, bsum, N);
    scan_bsums_k<<<1, 512, 0, stream>>>(bsum, bscan, nb);
    scan_final_k<<<nb, 256, 0, stream>>>(cnt, bscan, off, cursor, N);
    fill_k<<<(E + 255) / 256, 256, 0, stream>>>(ei, cursor, csr, E, N);

    // layer 1: A = x @ W1 ; Bf = relu(Agg(A) + b1)
    gemm256_k<<<dim3((N + 63) / 64, 4), 256, 0, stream>>>(x, W1, A, N, 128);
    aggregate_k<<<N, 256, 0, stream>>>(A, csr, off, cnt, dinv, b1, Bf, N);

    // layer 2: A = Bf @ W2 ; Bf = relu(Agg(A) + b2)
    gemm256_k<<<dim3((N + 63) / 64, 4), 256, 0, stream>>>(Bf, W2, A, N, 256);
    aggregate_k<<<N, 256, 0, stream>>>(A, csr, off, cnt, dinv, b2, Bf, N);

    // pool + final dot
    pool_partial_k<<<512, 256, 0, stream>>>(Bf, pool, N);
    final_k<<<1, 256, 0, stream>>>(pool, Wout, bout, out, 1.0f / N);
}

// Round 3
// 888.557 us; speedup vs baseline: 1.4395x; 1.4395x over previous
//
#include <hip/hip_runtime.h>
#include <hip/hip_bf16.h>

// ---------------------------------------------------------------------------
// GCN forward, reassociated:
//   X' = S.X           (gather on 128-wide input)
//   h1' = dinv .* relu(X'@W1 + b1)        (GEMM1 fused epilogue)
//   g  = S'.h1'        (gather, pre-scaled: g[i]=dinv[i]*(h1'[i]+sum h1'[src]))
//   pool = colsum(relu(g@W2 + b2))        (GEMM2 fused epilogue, no h2 buffer)
//   out = (pool/N).Wout + bout
// S = D^-1/2 (A+I) D^-1/2,  dinv[i] = rsqrt(in_deg[i]+1)
// ---------------------------------------------------------------------------

__global__ void count_k(const int* __restrict__ ei, int* __restrict__ cnt, int E, int N) {
    int e = blockIdx.x * blockDim.x + threadIdx.x;
    if (e < E) {
        unsigned d = (unsigned)ei[(size_t)E + e];
        if (d < (unsigned)N) atomicAdd(&cnt[d], 1);
    }
}

__global__ void dinv_k(const int* __restrict__ cnt, float* __restrict__ dinv, int n) {
    int i = blockIdx.x * blockDim.x + threadIdx.x;
    if (i < n) dinv[i] = rsqrtf((float)cnt[i] + 1.0f);
}

__global__ void block_sum_k(const int* __restrict__ cnt, int* __restrict__ bsum, int n) {
    __shared__ int s[256];
    int t = threadIdx.x;
    int idx = blockIdx.x * 256 + t;
    s[t] = (idx < n) ? cnt[idx] : 0;
    __syncthreads();
    for (int o = 128; o > 0; o >>= 1) {
        if (t < o) s[t] += s[t + o];
        __syncthreads();
    }
    if (t == 0) bsum[blockIdx.x] = s[0];
}

__global__ void scan_bsums_k(const int* __restrict__ bsum, int* __restrict__ bscan, int nb) {
    __shared__ int s[2][512];
    int t = threadIdx.x;
    int v = (t < nb) ? bsum[t] : 0;
    s[0][t] = v;
    __syncthreads();
    int cur = 0;
    for (int o = 1; o < 512; o <<= 1) {
        int val = s[cur][t];
        if (t >= o) val += s[cur][t - o];
        s[cur ^ 1][t] = val;
        cur ^= 1;
        __syncthreads();
    }
    if (t < nb) bscan[t] = s[cur][t] - v;  // exclusive
}

__global__ void scan_final_k(const int* __restrict__ cnt, const int* __restrict__ bscan,
                             int* __restrict__ off, int* __restrict__ cursor, int n) {
    __shared__ int s[2][256];
    int t = threadIdx.x;
    int idx = blockIdx.x * 256 + t;
    int v = (idx < n) ? cnt[idx] : 0;
    s[0][t] = v;
    __syncthreads();
    int cur = 0;
    for (int o = 1; o < 256; o <<= 1) {
        int val = s[cur][t];
        if (t >= o) val += s[cur][t - o];
        s[cur ^ 1][t] = val;
        cur ^= 1;
        __syncthreads();
    }
    int ex = s[cur][t] - v + bscan[blockIdx.x];
    if (idx < n) { off[idx] = ex; cursor[idx] = ex; }
}

__global__ void fill_k(const int* __restrict__ ei, int* __restrict__ cursor,
                       int* __restrict__ csr, int E, int N) {
    int e = blockIdx.x * blockDim.x + threadIdx.x;
    if (e < E) {
        unsigned d = (unsigned)ei[(size_t)E + e];
        unsigned s = (unsigned)ei[e];
        if (d < (unsigned)N && s < (unsigned)N) {
            int pos = atomicAdd(&cursor[d], 1);
            csr[pos] = (int)s;
        }
    }
}

// -------------------- aggregation: one wave per node ------------------------
// layer 1: O[i] = dinv[i]*( dinv[i]*X[i] + sum_e dinv[src]*X[src] ), width 128
__global__ __launch_bounds__(256) void agg128_k(const float* __restrict__ X,
                                                const int* __restrict__ csr,
                                                const int* __restrict__ off,
                                                const int* __restrict__ cnt,
                                                const float* __restrict__ dinv,
                                                float* __restrict__ O, int n) {
    int w = (blockIdx.x * 256 + threadIdx.x) >> 6;
    int lane = threadIdx.x & 63;
    if (w >= n) return;
    const float2* Xr = (const float2*)X;   // row stride 64 float2
    float di = dinv[w];
    float2 self = Xr[(size_t)w * 64 + lane];
    float a0x = di * self.x, a0y = di * self.y;
    float a1x = 0.f, a1y = 0.f, a2x = 0.f, a2y = 0.f, a3x = 0.f, a3y = 0.f;
    int st = off[w], c = cnt[w];
    int e = 0;
    for (; e + 4 <= c; e += 4) {
        int s0 = csr[st + e], s1 = csr[st + e + 1], s2 = csr[st + e + 2], s3 = csr[st + e + 3];
        float w0 = dinv[s0], w1 = dinv[s1], w2 = dinv[s2], w3 = dinv[s3];
        float2 r0 = Xr[(size_t)s0 * 64 + lane];
        float2 r1 = Xr[(size_t)s1 * 64 + lane];
        float2 r2 = Xr[(size_t)s2 * 64 + lane];
        float2 r3 = Xr[(size_t)s3 * 64 + lane];
        a0x += w0 * r0.x; a0y += w0 * r0.y;
        a1x += w1 * r1.x; a1y += w1 * r1.y;
        a2x += w2 * r2.x; a2y += w2 * r2.y;
        a3x += w3 * r3.x; a3y += w3 * r3.y;
    }
    for (; e < c; ++e) {
        int s = csr[st + e];
        float ws = dinv[s];
        float2 r = Xr[(size_t)s * 64 + lane];
        a0x += ws * r.x; a0y += ws * r.y;
    }
    float2 o;
    o.x = di * (a0x + a1x + a2x + a3x);
    o.y = di * (a0y + a1y + a2y + a3y);
    ((float2*)O)[(size_t)w * 64 + lane] = o;
}

// layer 2: H is pre-scaled (h1' = dinv.*h1): O[i] = dinv[i]*(H[i]+sum H[src]), width 256
__global__ __launch_bounds__(256) void agg256_k(const float* __restrict__ H,
                                                const int* __restrict__ csr,
                                                const int* __restrict__ off,
                                                const int* __restrict__ cnt,
                                                const float* __restrict__ dinv,
                                                float* __restrict__ O, int n) {
    int w = (blockIdx.x * 256 + threadIdx.x) >> 6;
    int lane = threadIdx.x & 63;
    if (w >= n) return;
    const float4* Hr = (const float4*)H;   // row stride 64 float4
    float di = dinv[w];
    float4 a0 = Hr[(size_t)w * 64 + lane];   // self term, already scaled
    float4 a1 = make_float4(0.f, 0.f, 0.f, 0.f);
    float4 a2 = a1, a3 = a1;
    int st = off[w], c = cnt[w];
    int e = 0;
    for (; e + 4 <= c; e += 4) {
        int s0 = csr[st + e], s1 = csr[st + e + 1], s2 = csr[st + e + 2], s3 = csr[st + e + 3];
        float4 r0 = Hr[(size_t)s0 * 64 + lane];
        float4 r1 = Hr[(size_t)s1 * 64 + lane];
        float4 r2 = Hr[(size_t)s2 * 64 + lane];
        float4 r3 = Hr[(size_t)s3 * 64 + lane];
        a0.x += r0.x; a0.y += r0.y; a0.z += r0.z; a0.w += r0.w;
        a1.x += r1.x; a1.y += r1.y; a1.z += r1.z; a1.w += r1.w;
        a2.x += r2.x; a2.y += r2.y; a2.z += r2.z; a2.w += r2.w;
        a3.x += r3.x; a3.y += r3.y; a3.z += r3.z; a3.w += r3.w;
    }
    for (; e < c; ++e) {
        int s = csr[st + e];
        float4 r = Hr[(size_t)s * 64 + lane];
        a0.x += r.x; a0.y += r.y; a0.z += r.z; a0.w += r.w;
    }
    float4 o;
    o.x = di * (a0.x + a1.x + a2.x + a3.x);
    o.y = di * (a0.y + a1.y + a2.y + a3.y);
    o.z = di * (a0.z + a1.z + a2.z + a3.z);
    o.w = di * (a0.w + a1.w + a2.w + a3.w);
    ((float4*)O)[(size_t)w * 64 + lane] = o;
}

// -------------------- GEMM with fused epilogues -----------------------------
// H[M,256] = X[M,K] @ W[K,256]; 64x64 tile, BK=32, 4x4/thread.
// MODE 1: H[r][c] = dinv[r]*relu(acc + bias[c])      (layer-1 output, pre-scaled)
// MODE 2: pool[c] += sum_r relu(acc + bias[c])       (layer-2, no H written)
template <int MODE>
__global__ __launch_bounds__(256) void gemm_k(const float* __restrict__ X,
                                              const float* __restrict__ W,
                                              const float* __restrict__ bias,
                                              const float* __restrict__ dinv,
                                              float* __restrict__ H,
                                              float* __restrict__ pool,
                                              int M, int K) {
    __shared__ float As[64][33];
    __shared__ float Bs[32][64];
    int tid = threadIdx.x;
    int tx = tid & 15, ty = tid >> 4;
    int row0 = blockIdx.x * 64, col0 = blockIdx.y * 64;
    float c[4][4] = {};

    for (int kt = 0; kt < K; kt += 32) {
#pragma unroll
        for (int l = 0; l < 2; ++l) {
            int f = tid + l * 256;
            int r = f >> 3;
            int kc = (f & 7) << 2;
            float4 v = make_float4(0.f, 0.f, 0.f, 0.f);
            int gr = row0 + r;
            if (gr < M) v = *(const float4*)(X + (size_t)gr * K + kt + kc);
            As[r][kc + 0] = v.x; As[r][kc + 1] = v.y;
            As[r][kc + 2] = v.z; As[r][kc + 3] = v.w;
        }
#pragma unroll
        for (int l = 0; l < 2; ++l) {
            int f = tid + l * 256;
            int r = f >> 4;
            int c4 = (f & 15) << 2;
            float4 w = *(const float4*)(W + (size_t)(kt + r) * 256 + col0 + c4);
            *(float4*)&Bs[r][c4] = w;
        }
        __syncthreads();
#pragma unroll
        for (int kk = 0; kk < 32; ++kk) {
            float a0 = As[ty * 4 + 0][kk];
            float a1 = As[ty * 4 + 1][kk];
            float a2 = As[ty * 4 + 2][kk];
            float a3 = As[ty * 4 + 3][kk];
            float4 b = *(const float4*)&Bs[kk][tx << 2];
            c[0][0] += a0 * b.x; c[0][1] += a0 * b.y; c[0][2] += a0 * b.z; c[0][3] += a0 * b.w;
            c[1][0] += a1 * b.x; c[1][1] += a1 * b.y; c[1][2] += a1 * b.z; c[1][3] += a1 * b.w;
            c[2][0] += a2 * b.x; c[2][1] += a2 * b.y; c[2][2] += a2 * b.z; c[2][3] += a2 * b.w;
            c[3][0] += a3 * b.x; c[3][1] += a3 * b.y; c[3][2] += a3 * b.z; c[3][3] += a3 * b.w;
        }
        __syncthreads();
    }

    float bv[4];
#pragma unroll
    for (int j = 0; j < 4; ++j) bv[j] = bias[col0 + (tx << 2) + j];

    if (MODE == 1) {
#pragma unroll
        for (int i = 0; i < 4; ++i) {
            int gr = row0 + ty * 4 + i;
            if (gr < M) {
                float dr = dinv[gr];
                float4 v;
                v.x = dr * fmaxf(c[i][0] + bv[0], 0.f);
                v.y = dr * fmaxf(c[i][1] + bv[1], 0.f);
                v.z = dr * fmaxf(c[i][2] + bv[2], 0.f);
                v.w = dr * fmaxf(c[i][3] + bv[3], 0.f);
                *(float4*)(H + (size_t)gr * 256 + col0 + (tx << 2)) = v;
            }
        }
    } else {
        // column partial sums over this block's 64 rows (valid rows only)
        __shared__ float red[16][68];
        float s[4] = {0.f, 0.f, 0.f, 0.f};
#pragma unroll
        for (int i = 0; i < 4; ++i) {
            int gr = row0 + ty * 4 + i;
            if (gr < M) {
#pragma unroll
                for (int j = 0; j < 4; ++j)
                    s[j] += fmaxf(c[i][j] + bv[j], 0.f);
            }
        }
#pragma unroll
        for (int j = 0; j < 4; ++j) red[ty][(tx << 2) + j] = s[j];
        __syncthreads();
        if (tid < 64) {
            float t = 0.f;
#pragma unroll
            for (int r = 0; r < 16; ++r) t += red[r][tid];
            atomicAdd(&pool[col0 + tid], t);
        }
    }
}

__global__ void final_k(const float* __restrict__ pool, const float* __restrict__ Wout,
                        const float* __restrict__ bout, float* __restrict__ out, float invM) {
    __shared__ float s[256];
    int t = threadIdx.x;
    s[t] = pool[t] * invM * Wout[t];
    __syncthreads();
    for (int o = 128; o > 0; o >>= 1) {
        if (t < o) s[t] += s[t + o];
        __syncthreads();
    }
    if (t == 0) out[0] = s[0] + bout[0];
}

extern "C" void kernel_launch(void* const* d_in, const int* in_sizes, int n_in,
                              void* d_out, int out_size, void* d_ws, size_t ws_size,
                              hipStream_t stream) {
    const float* x    = (const float*)d_in[0];
    const int*   ei   = (const int*)d_in[1];      // int32 per harness conversion
    const float* W1   = (const float*)d_in[2];
    const float* b1   = (const float*)d_in[3];
    const float* W2   = (const float*)d_in[4];
    const float* b2   = (const float*)d_in[5];
    const float* Wout = (const float*)d_in[6];
    const float* bout = (const float*)d_in[7];
    float* out = (float*)d_out;

    const int N = in_sizes[0] / 128;       // 100000
    const int E = in_sizes[1] / 2;         // 1600000
    const int nb = (N + 255) / 256;        // scan blocks

    char* p = (char*)d_ws;
    auto carve = [&](size_t bytes) -> void* {
        void* r = (void*)p;
        p += (bytes + 511) & ~(size_t)511;
        return r;
    };
    float* A      = (float*)carve((size_t)N * 256 * 4);  // X' (N,128) then g (N,256)
    float* Bf     = (float*)carve((size_t)N * 256 * 4);  // h1' (N,256)
    float* dinv   = (float*)carve((size_t)N * 4);
    int*   cnt    = (int*)carve((size_t)N * 4);
    int*   off    = (int*)carve((size_t)(N + 1) * 4);
    int*   cursor = (int*)carve((size_t)N * 4);
    int*   csr    = (int*)carve((size_t)E * 4);
    int*   bsum   = (int*)carve((size_t)nb * 4);
    int*   bscan  = (int*)carve((size_t)nb * 4);
    float* pool   = (float*)carve(256 * 4);

    hipMemsetAsync(cnt, 0, (size_t)N * 4, stream);
    hipMemsetAsync(pool, 0, 256 * 4, stream);

    count_k<<<(E + 255) / 256, 256, 0, stream>>>(ei, cnt, E, N);
    dinv_k<<<(N + 255) / 256, 256, 0, stream>>>(cnt, dinv, N);
    block_sum_k<<<nb, 256, 0, stream>>>(cnt, bsum, N);
    scan_bsums_k<<<1, 512, 0, stream>>>(bsum, bscan, nb);
    scan_final_k<<<nb, 256, 0, stream>>>(cnt, bscan, off, cursor, N);
    fill_k<<<(E + 255) / 256, 256, 0, stream>>>(ei, cursor, csr, E, N);

    // layer 1: X' = S.X (128-wide gather), then h1' = dinv.*relu(X'@W1+b1)
    agg128_k<<<(N + 3) / 4, 256, 0, stream>>>(x, csr, off, cnt, dinv, A, N);
    gemm_k<1><<<dim3((N + 63) / 64, 4), 256, 0, stream>>>(A, W1, b1, dinv, Bf, nullptr, N, 128);

    // layer 2: g = S'.h1' (256-wide gather, pre-scaled), then pooled GEMM
    agg256_k<<<(N + 3) / 4, 256, 0, stream>>>(Bf, csr, off, cnt, dinv, A, N);
    gemm_k<2><<<dim3((N + 63) / 64, 4), 256, 0, stream>>>(A, W2, b2, nullptr, nullptr, pool, N, 256);

    final_k<<<1, 256, 0, stream>>>(pool, Wout, bout, out, 1.0f / N);
}

// Round 4
// 558.743 us; speedup vs baseline: 2.2892x; 1.5903x over previous
//
#include <hip/hip_runtime.h>
#include <hip/hip_bf16.h>

// ---------------------------------------------------------------------------
// GCN forward, reassociated, bf16 data path (validation is bf16-rounded):
//   Xs = (dinv .* x)              bf16  [N,128]
//   X' = dinv .* (Xs_self + sum_e Xs[src])   (agg128)        bf16 [N,128]
//   h1' = dinv .* relu(X'@W1 + b1)           (MFMA GEMM1)    bf16 [N,256]
//   g  = dinv .* (h1'_self + sum_e h1'[src]) (agg256)        bf16 [N,256]
//   pool = colsum(relu(g@W2 + b2))           (MFMA GEMM2, fused, no h2)
//   out = (pool/N)@Wout + bout
// ---------------------------------------------------------------------------

typedef __attribute__((ext_vector_type(8))) short short8;
typedef __attribute__((ext_vector_type(4))) float f32x4;

__device__ inline float bf2f(unsigned short u) {
    union { unsigned u; float f; } v; v.u = (unsigned)u << 16; return v.f;
}
__device__ inline unsigned short f2bf(float f) {
    union { float f; unsigned u; } v; v.f = f;
    unsigned r = (v.u + 0x7fff + ((v.u >> 16) & 1)) >> 16;
    return (unsigned short)r;
}

// ----------------------------- CSR build ------------------------------------
__global__ void count_k(const int* __restrict__ ei, int* __restrict__ cnt, int E, int N) {
    int e = blockIdx.x * blockDim.x + threadIdx.x;
    if (e < E) {
        unsigned d = (unsigned)ei[(size_t)E + e];
        if (d < (unsigned)N) atomicAdd(&cnt[d], 1);
    }
}

__global__ void dinv_k(const int* __restrict__ cnt, float* __restrict__ dinv, int n) {
    int i = blockIdx.x * blockDim.x + threadIdx.x;
    if (i < n) dinv[i] = rsqrtf((float)cnt[i] + 1.0f);
}

__global__ void block_sum_k(const int* __restrict__ cnt, int* __restrict__ bsum, int n) {
    __shared__ int s[256];
    int t = threadIdx.x;
    int idx = blockIdx.x * 256 + t;
    s[t] = (idx < n) ? cnt[idx] : 0;
    __syncthreads();
    for (int o = 128; o > 0; o >>= 1) {
        if (t < o) s[t] += s[t + o];
        __syncthreads();
    }
    if (t == 0) bsum[blockIdx.x] = s[0];
}

__global__ void scan_bsums_k(const int* __restrict__ bsum, int* __restrict__ bscan, int nb) {
    __shared__ int s[2][512];
    int t = threadIdx.x;
    int v = (t < nb) ? bsum[t] : 0;
    s[0][t] = v;
    __syncthreads();
    int cur = 0;
    for (int o = 1; o < 512; o <<= 1) {
        int val = s[cur][t];
        if (t >= o) val += s[cur][t - o];
        s[cur ^ 1][t] = val;
        cur ^= 1;
        __syncthreads();
    }
    if (t < nb) bscan[t] = s[cur][t] - v;  // exclusive
}

__global__ void scan_final_k(const int* __restrict__ cnt, const int* __restrict__ bscan,
                             int* __restrict__ off, int* __restrict__ cursor, int n) {
    __shared__ int s[2][256];
    int t = threadIdx.x;
    int idx = blockIdx.x * 256 + t;
    int v = (idx < n) ? cnt[idx] : 0;
    s[0][t] = v;
    __syncthreads();
    int cur = 0;
    for (int o = 1; o < 256; o <<= 1) {
        int val = s[cur][t];
        if (t >= o) val += s[cur][t - o];
        s[cur ^ 1][t] = val;
        cur ^= 1;
        __syncthreads();
    }
    int ex = s[cur][t] - v + bscan[blockIdx.x];
    if (idx < n) { off[idx] = ex; cursor[idx] = ex; }
}

__global__ void fill_k(const int* __restrict__ ei, int* __restrict__ cursor,
                       int* __restrict__ csr, int E, int N) {
    int e = blockIdx.x * blockDim.x + threadIdx.x;
    if (e < E) {
        unsigned d = (unsigned)ei[(size_t)E + e];
        unsigned s = (unsigned)ei[e];
        if (d < (unsigned)N && s < (unsigned)N) {
            int pos = atomicAdd(&cursor[d], 1);
            csr[pos] = (int)s;
        }
    }
}

// ----------------------------- conversions ----------------------------------
// Xs[i] = bf16(dinv[i] * x[i]); one thread per float2 (packs 1 uint)
__global__ void cvtx_k(const float* __restrict__ x, const float* __restrict__ dinv,
                       unsigned* __restrict__ Xs, int n64) {
    int idx = blockIdx.x * 256 + threadIdx.x;
    if (idx >= n64) return;
    int i = idx >> 6;
    float2 v = ((const float2*)x)[idx];
    float di = dinv[i];
    Xs[idx] = (unsigned)f2bf(di * v.x) | ((unsigned)f2bf(di * v.y) << 16);
}

// W[K][256] fp32 -> Wt[256][K] bf16
__global__ void wt_k(const float* __restrict__ W, unsigned short* __restrict__ Wt, int K) {
    int idx = blockIdx.x * 256 + threadIdx.x;
    if (idx >= K * 256) return;
    int k = idx >> 8, nn = idx & 255;
    Wt[nn * K + k] = f2bf(W[idx]);
}

// --------------------- aggregation (one wave per node) ----------------------
// width 128 bf16 (row = 64 uints); O[i] = bf16( dinv[i]*(X[i] + sum X[src]) )
__global__ __launch_bounds__(256) void agg128_k(const unsigned* __restrict__ X,
                                                const int* __restrict__ csr,
                                                const int* __restrict__ off,
                                                const int* __restrict__ cnt,
                                                const float* __restrict__ dinv,
                                                unsigned* __restrict__ O, int n) {
    int w = (blockIdx.x * 256 + threadIdx.x) >> 6;
    int lane = threadIdx.x & 63;
    if (w >= n) return;
    unsigned self = X[(size_t)w * 64 + lane];
    float a0x = bf2f(self & 0xffff), a0y = bf2f(self >> 16);
    float a1x = 0.f, a1y = 0.f, a2x = 0.f, a2y = 0.f, a3x = 0.f, a3y = 0.f;
    int st = off[w], c = cnt[w];
    int e = 0;
    for (; e + 4 <= c; e += 4) {
        int s0 = csr[st + e], s1 = csr[st + e + 1], s2 = csr[st + e + 2], s3 = csr[st + e + 3];
        unsigned u0 = X[(size_t)s0 * 64 + lane];
        unsigned u1 = X[(size_t)s1 * 64 + lane];
        unsigned u2 = X[(size_t)s2 * 64 + lane];
        unsigned u3 = X[(size_t)s3 * 64 + lane];
        a0x += bf2f(u0 & 0xffff); a0y += bf2f(u0 >> 16);
        a1x += bf2f(u1 & 0xffff); a1y += bf2f(u1 >> 16);
        a2x += bf2f(u2 & 0xffff); a2y += bf2f(u2 >> 16);
        a3x += bf2f(u3 & 0xffff); a3y += bf2f(u3 >> 16);
    }
    for (; e < c; ++e) {
        int s = csr[st + e];
        unsigned u = X[(size_t)s * 64 + lane];
        a0x += bf2f(u & 0xffff); a0y += bf2f(u >> 16);
    }
    float di = dinv[w];
    float ox = di * (a0x + a1x + a2x + a3x);
    float oy = di * (a0y + a1y + a2y + a3y);
    O[(size_t)w * 64 + lane] = (unsigned)f2bf(ox) | ((unsigned)f2bf(oy) << 16);
}

// width 256 bf16 (row = 64 uint2); H pre-scaled: O[i] = bf16( dinv[i]*(H[i]+sum H[src]) )
__global__ __launch_bounds__(256) void agg256_k(const uint2* __restrict__ H,
                                                const int* __restrict__ csr,
                                                const int* __restrict__ off,
                                                const int* __restrict__ cnt,
                                                const float* __restrict__ dinv,
                                                uint2* __restrict__ O, int n) {
    int w = (blockIdx.x * 256 + threadIdx.x) >> 6;
    int lane = threadIdx.x & 63;
    if (w >= n) return;
    uint2 self = H[(size_t)w * 64 + lane];
    float a0 = bf2f(self.x & 0xffff), a1 = bf2f(self.x >> 16);
    float a2 = bf2f(self.y & 0xffff), a3 = bf2f(self.y >> 16);
    float b0 = 0.f, b1 = 0.f, b2 = 0.f, b3 = 0.f;
    float c0 = 0.f, c1 = 0.f, c2 = 0.f, c3 = 0.f;
    float d0 = 0.f, d1 = 0.f, d2 = 0.f, d3 = 0.f;
    int st = off[w], c = cnt[w];
    int e = 0;
    for (; e + 4 <= c; e += 4) {
        int s0 = csr[st + e], s1 = csr[st + e + 1], s2 = csr[st + e + 2], s3 = csr[st + e + 3];
        uint2 r0 = H[(size_t)s0 * 64 + lane];
        uint2 r1 = H[(size_t)s1 * 64 + lane];
        uint2 r2 = H[(size_t)s2 * 64 + lane];
        uint2 r3 = H[(size_t)s3 * 64 + lane];
        a0 += bf2f(r0.x & 0xffff); a1 += bf2f(r0.x >> 16); a2 += bf2f(r0.y & 0xffff); a3 += bf2f(r0.y >> 16);
        b0 += bf2f(r1.x & 0xffff); b1 += bf2f(r1.x >> 16); b2 += bf2f(r1.y & 0xffff); b3 += bf2f(r1.y >> 16);
        c0 += bf2f(r2.x & 0xffff); c1 += bf2f(r2.x >> 16); c2 += bf2f(r2.y & 0xffff); c3 += bf2f(r2.y >> 16);
        d0 += bf2f(r3.x & 0xffff); d1 += bf2f(r3.x >> 16); d2 += bf2f(r3.y & 0xffff); d3 += bf2f(r3.y >> 16);
    }
    for (; e < c; ++e) {
        int s = csr[st + e];
        uint2 r = H[(size_t)s * 64 + lane];
        a0 += bf2f(r.x & 0xffff); a1 += bf2f(r.x >> 16);
        a2 += bf2f(r.y & 0xffff); a3 += bf2f(r.y >> 16);
    }
    float di = dinv[w];
    float o0 = di * (a0 + b0 + c0 + d0);
    float o1 = di * (a1 + b1 + c1 + d1);
    float o2 = di * (a2 + b2 + c2 + d2);
    float o3 = di * (a3 + b3 + c3 + d3);
    uint2 o;
    o.x = (unsigned)f2bf(o0) | ((unsigned)f2bf(o1) << 16);
    o.y = (unsigned)f2bf(o2) | ((unsigned)f2bf(o3) << 16);
    O[(size_t)w * 64 + lane] = o;
}

// ------------------------- MFMA bf16 GEMM -----------------------------------
// C[M,256] = A[M,K](bf16) @ Bt[256,K](bf16)^T ; tile 64x64, 4 waves, K_STEP=32.
// MFMA 16x16x32: A-frag lane: A[m=l&15][k=(l>>4)*8+j]; B-frag: Bt[n=l&15][k=..];
// D: row=(l>>4)*4+r, col=l&15 (guide m89/m91 verified convention).
// MODE 1: Hout[r][c] = bf16( dinv[r]*relu(acc+bias[c]) )
// MODE 2: pool[c] += sum_r relu(acc+bias[c])   (no Hout)
template <int MODE>
__global__ __launch_bounds__(256) void mgemm_k(const unsigned short* __restrict__ A,
                                               const unsigned short* __restrict__ Bt,
                                               const float* __restrict__ bias,
                                               const float* __restrict__ dinv,
                                               unsigned short* __restrict__ Hout,
                                               float* __restrict__ pool,
                                               int M, int K) {
    __shared__ __align__(16) short As[64 * 40];   // +8 pad: 2-way banks (free)
    __shared__ __align__(16) short Bs[64 * 40];
    int tid = threadIdx.x;
    int w = tid >> 6, lane = tid & 63, lr = lane >> 4, lc = lane & 15;
    int row0 = blockIdx.x * 64, col0 = blockIdx.y * 64;
    int srow = tid >> 2, skoff = (tid & 3) * 8;
    f32x4 acc[4] = {};

    for (int kt = 0; kt < K; kt += 32) {
        short8 va = {};
        int gr = row0 + srow;
        if (gr < M) va = *(const short8*)(A + (size_t)gr * K + kt + skoff);
        *(short8*)&As[srow * 40 + skoff] = va;
        short8 vb = *(const short8*)(Bt + (size_t)(col0 + srow) * K + kt + skoff);
        *(short8*)&Bs[srow * 40 + skoff] = vb;
        __syncthreads();
        short8 af = *(const short8*)&As[(w * 16 + lc) * 40 + lr * 8];
#pragma unroll
        for (int f = 0; f < 4; ++f) {
            short8 bf = *(const short8*)&Bs[(f * 16 + lc) * 40 + lr * 8];
            acc[f] = __builtin_amdgcn_mfma_f32_16x16x32_bf16(af, bf, acc[f], 0, 0, 0);
        }
        __syncthreads();
    }

    float bv[4];
#pragma unroll
    for (int f = 0; f < 4; ++f) bv[f] = bias[col0 + f * 16 + lc];

    if (MODE == 1) {
#pragma unroll
        for (int r = 0; r < 4; ++r) {
            int gr = row0 + w * 16 + lr * 4 + r;
            if (gr < M) {
                float dr = dinv[gr];
#pragma unroll
                for (int f = 0; f < 4; ++f) {
                    float v = dr * fmaxf(acc[f][r] + bv[f], 0.f);
                    Hout[(size_t)gr * 256 + col0 + f * 16 + lc] = f2bf(v);
                }
            }
        }
    } else {
        __shared__ float red[16][64];
        float s[4] = {0.f, 0.f, 0.f, 0.f};
#pragma unroll
        for (int r = 0; r < 4; ++r) {
            int gr = row0 + w * 16 + lr * 4 + r;
            if (gr < M) {
#pragma unroll
                for (int f = 0; f < 4; ++f)
                    s[f] += fmaxf(acc[f][r] + bv[f], 0.f);
            }
        }
#pragma unroll
        for (int f = 0; f < 4; ++f) red[w * 4 + lr][f * 16 + lc] = s[f];
        __syncthreads();
        if (tid < 64) {
            float t = 0.f;
#pragma unroll
            for (int rr = 0; rr < 16; ++rr) t += red[rr][tid];
            atomicAdd(&pool[col0 + tid], t);
        }
    }
}

__global__ void final_k(const float* __restrict__ pool, const float* __restrict__ Wout,
                        const float* __restrict__ bout, float* __restrict__ out, float invM) {
    __shared__ float s[256];
    int t = threadIdx.x;
    s[t] = pool[t] * invM * Wout[t];
    __syncthreads();
    for (int o = 128; o > 0; o >>= 1) {
        if (t < o) s[t] += s[t + o];
        __syncthreads();
    }
    if (t == 0) out[0] = s[0] + bout[0];
}

extern "C" void kernel_launch(void* const* d_in, const int* in_sizes, int n_in,
                              void* d_out, int out_size, void* d_ws, size_t ws_size,
                              hipStream_t stream) {
    const float* x    = (const float*)d_in[0];
    const int*   ei   = (const int*)d_in[1];      // int32 per harness conversion
    const float* W1   = (const float*)d_in[2];
    const float* b1   = (const float*)d_in[3];
    const float* W2   = (const float*)d_in[4];
    const float* b2   = (const float*)d_in[5];
    const float* Wout = (const float*)d_in[6];
    const float* bout = (const float*)d_in[7];
    float* out = (float*)d_out;

    const int N = in_sizes[0] / 128;       // 100000
    const int E = in_sizes[1] / 2;         // 1600000
    const int nb = (N + 255) / 256;

    char* p = (char*)d_ws;
    auto carve = [&](size_t bytes) -> void* {
        void* r = (void*)p;
        p += (bytes + 511) & ~(size_t)511;
        return r;
    };
    unsigned*       Xs   = (unsigned*)carve((size_t)N * 128 * 2);        // dinv.*x bf16
    unsigned*       Xp   = (unsigned*)carve((size_t)N * 128 * 2);        // X' bf16
    unsigned short* H1   = (unsigned short*)carve((size_t)N * 256 * 2);  // h1' bf16
    unsigned short* G    = (unsigned short*)carve((size_t)N * 256 * 2);  // g bf16
    unsigned short* Wt1  = (unsigned short*)carve((size_t)128 * 256 * 2);
    unsigned short* Wt2  = (unsigned short*)carve((size_t)256 * 256 * 2);
    float* dinv   = (float*)carve((size_t)N * 4);
    int*   cnt    = (int*)carve((size_t)N * 4);
    int*   off    = (int*)carve((size_t)(N + 1) * 4);
    int*   cursor = (int*)carve((size_t)N * 4);
    int*   csr    = (int*)carve((size_t)E * 4);
    int*   bsum   = (int*)carve((size_t)nb * 4);
    int*   bscan  = (int*)carve((size_t)nb * 4);
    float* pool   = (float*)carve(256 * 4);

    hipMemsetAsync(cnt, 0, (size_t)N * 4, stream);
    hipMemsetAsync(pool, 0, 256 * 4, stream);

    count_k<<<(E + 255) / 256, 256, 0, stream>>>(ei, cnt, E, N);
    dinv_k<<<(N + 255) / 256, 256, 0, stream>>>(cnt, dinv, N);
    cvtx_k<<<(N * 64 + 255) / 256, 256, 0, stream>>>(x, dinv, Xs, N * 64);
    wt_k<<<(128 * 256 + 255) / 256, 256, 0, stream>>>(W1, Wt1, 128);
    wt_k<<<(256 * 256 + 255) / 256, 256, 0, stream>>>(W2, Wt2, 256);
    block_sum_k<<<nb, 256, 0, stream>>>(cnt, bsum, N);
    scan_bsums_k<<<1, 512, 0, stream>>>(bsum, bscan, nb);
    scan_final_k<<<nb, 256, 0, stream>>>(cnt, bscan, off, cursor, N);
    fill_k<<<(E + 255) / 256, 256, 0, stream>>>(ei, cursor, csr, E, N);

    // layer 1
    agg128_k<<<(N + 3) / 4, 256, 0, stream>>>(Xs, csr, off, cnt, dinv, Xp, N);
    mgemm_k<1><<<dim3((N + 63) / 64, 4), 256, 0, stream>>>(
        (const unsigned short*)Xp, Wt1, b1, dinv, H1, nullptr, N, 128);

    // layer 2
    agg256_k<<<(N + 3) / 4, 256, 0, stream>>>((const uint2*)H1, csr, off, cnt, dinv, (uint2*)G, N);
    mgemm_k<2><<<dim3((N + 63) / 64, 4), 256, 0, stream>>>(
        G, Wt2, b2, nullptr, nullptr, pool, N, 256);

    final_k<<<1, 256, 0, stream>>>(pool, Wout, bout, out, 1.0f / N);
}

// Round 5
// 466.323 us; speedup vs baseline: 2.7428x; 1.1982x over previous
//
#include <hip/hip_runtime.h>
#include <hip/hip_bf16.h>

// ---------------------------------------------------------------------------
// GCN forward, reassociated, bf16 data path:
//   Xs = (dinv .* x)              bf16  [N,128]
//   X' = dinv .* (Xs_self + sum_e Xs[src])   (agg128)        bf16 [N,128]
//   h1' = dinv .* relu(X'@W1 + b1)           (MFMA GEMM1)    bf16 [N,256]
//   g  = dinv .* (h1'_self + sum_e h1'[src]) (agg256)        bf16 [N,256]
//   pool = colsum(relu(g@W2 + b2))           (MFMA GEMM2, fused, no h2)
//   out = (pool/N)@Wout + bout
// CSR build: count -> scan -> bucketed two-pass fill (bin_k + scatter_k)
// to avoid the 16x write amplification of a fully random 4B scatter.
// ---------------------------------------------------------------------------

typedef __attribute__((ext_vector_type(8))) short short8;
typedef __attribute__((ext_vector_type(4))) float f32x4;

#define BKT_SHIFT 9
#define BKT_NODES 512
#define BIN_CHUNK 8192

__device__ inline float bf2f(unsigned short u) {
    union { unsigned u; float f; } v; v.u = (unsigned)u << 16; return v.f;
}
__device__ inline unsigned short f2bf(float f) {
    union { float f; unsigned u; } v; v.f = f;
    unsigned r = (v.u + 0x7fff + ((v.u >> 16) & 1)) >> 16;
    return (unsigned short)r;
}

// ----------------------------- CSR build ------------------------------------
__global__ void count_k(const int* __restrict__ ei, int* __restrict__ cnt, int E, int N) {
    int e = blockIdx.x * blockDim.x + threadIdx.x;
    if (e < E) {
        unsigned d = (unsigned)ei[(size_t)E + e];
        if (d < (unsigned)N) atomicAdd(&cnt[d], 1);
    }
}

__global__ void dinv_k(const int* __restrict__ cnt, float* __restrict__ dinv, int n) {
    int i = blockIdx.x * blockDim.x + threadIdx.x;
    if (i < n) dinv[i] = rsqrtf((float)cnt[i] + 1.0f);
}

__global__ void block_sum_k(const int* __restrict__ cnt, int* __restrict__ bsum, int n) {
    __shared__ int s[256];
    int t = threadIdx.x;
    int idx = blockIdx.x * 256 + t;
    s[t] = (idx < n) ? cnt[idx] : 0;
    __syncthreads();
    for (int o = 128; o > 0; o >>= 1) {
        if (t < o) s[t] += s[t + o];
        __syncthreads();
    }
    if (t == 0) bsum[blockIdx.x] = s[0];
}

__global__ void scan_bsums_k(const int* __restrict__ bsum, int* __restrict__ bscan, int nb) {
    __shared__ int s[2][512];
    int t = threadIdx.x;
    int v = (t < nb) ? bsum[t] : 0;
    s[0][t] = v;
    __syncthreads();
    int cur = 0;
    for (int o = 1; o < 512; o <<= 1) {
        int val = s[cur][t];
        if (t >= o) val += s[cur][t - o];
        s[cur ^ 1][t] = val;
        cur ^= 1;
        __syncthreads();
    }
    if (t < nb) bscan[t] = s[cur][t] - v;  // exclusive
}

__global__ void scan_final_k(const int* __restrict__ cnt, const int* __restrict__ bscan,
                             int* __restrict__ off, int n) {
    __shared__ int s[2][256];
    int t = threadIdx.x;
    int idx = blockIdx.x * 256 + t;
    int v = (idx < n) ? cnt[idx] : 0;
    s[0][t] = v;
    __syncthreads();
    int cur = 0;
    for (int o = 1; o < 256; o <<= 1) {
        int val = s[cur][t];
        if (t >= o) val += s[cur][t - o];
        s[cur ^ 1][t] = val;
        cur ^= 1;
        __syncthreads();
    }
    int ex = s[cur][t] - v + bscan[blockIdx.x];
    if (idx < n) {
        off[idx] = ex;
        if (idx == n - 1) off[n] = ex + v;   // total valid edges
    }
}

__global__ void bcur_k(const int* __restrict__ off, int* __restrict__ bcur, int NB) {
    int b = blockIdx.x * 256 + threadIdx.x;
    if (b < NB) bcur[b] = off[b << BKT_SHIFT];
}

// pass 1: bucket-binned pair staging. One block per 8192-edge chunk.
__global__ __launch_bounds__(256) void bin_k(const int* __restrict__ ei,
                                             int* __restrict__ bcur,
                                             uint2* __restrict__ pairs,
                                             int E, int N, int NB) {
    __shared__ int hist[256];
    __shared__ int base[256];
    int chunk0 = blockIdx.x * BIN_CHUNK;
    for (int t = threadIdx.x; t < NB; t += 256) hist[t] = 0;
    __syncthreads();
#pragma unroll 4
    for (int i = 0; i < BIN_CHUNK / 256; ++i) {
        int e = chunk0 + i * 256 + threadIdx.x;
        if (e < E) {
            unsigned d = (unsigned)ei[(size_t)E + e];
            if (d < (unsigned)N) atomicAdd(&hist[d >> BKT_SHIFT], 1);
        }
    }
    __syncthreads();
    for (int t = threadIdx.x; t < NB; t += 256) {
        int c = hist[t];
        base[t] = c ? atomicAdd(&bcur[t], c) : 0;
        hist[t] = 0;
    }
    __syncthreads();
#pragma unroll 4
    for (int i = 0; i < BIN_CHUNK / 256; ++i) {
        int e = chunk0 + i * 256 + threadIdx.x;
        if (e < E) {
            unsigned d = (unsigned)ei[(size_t)E + e];
            unsigned s = (unsigned)ei[e];
            if (d < (unsigned)N && s < (unsigned)N) {
                int b = d >> BKT_SHIFT;
                int r = atomicAdd(&hist[b], 1);
                pairs[base[b] + r] = make_uint2(s, d);
            }
        }
    }
}

// pass 2: one block per bucket; LDS per-node cursors; localized csr writes.
__global__ __launch_bounds__(256) void scatter_k(const uint2* __restrict__ pairs,
                                                 const int* __restrict__ off,
                                                 int* __restrict__ csr, int N) {
    __shared__ int cur[BKT_NODES];
    int b = blockIdx.x;
    int lo = b << BKT_SHIFT;
    int hi = min(lo + BKT_NODES, N);
    for (int t = threadIdx.x; t < hi - lo; t += 256) cur[t] = off[lo + t];
    __syncthreads();
    int rs = off[lo], re = off[hi];
    for (int i = rs + threadIdx.x; i < re; i += 256) {
        uint2 p = pairs[i];
        int pos = atomicAdd(&cur[p.y - lo], 1);
        csr[pos] = (int)p.x;
    }
}

// ----------------------------- conversions ----------------------------------
__global__ void cvtx_k(const float* __restrict__ x, const float* __restrict__ dinv,
                       unsigned* __restrict__ Xs, int n64) {
    int idx = blockIdx.x * 256 + threadIdx.x;
    if (idx >= n64) return;
    int i = idx >> 6;
    float2 v = ((const float2*)x)[idx];
    float di = dinv[i];
    Xs[idx] = (unsigned)f2bf(di * v.x) | ((unsigned)f2bf(di * v.y) << 16);
}

__global__ void wt_k(const float* __restrict__ W, unsigned short* __restrict__ Wt, int K) {
    int idx = blockIdx.x * 256 + threadIdx.x;
    if (idx >= K * 256) return;
    int k = idx >> 8, nn = idx & 255;
    Wt[nn * K + k] = f2bf(W[idx]);
}

// --------------------- aggregation (one wave per node) ----------------------
__global__ __launch_bounds__(256) void agg128_k(const unsigned* __restrict__ X,
                                                const int* __restrict__ csr,
                                                const int* __restrict__ off,
                                                const int* __restrict__ cnt,
                                                const float* __restrict__ dinv,
                                                unsigned* __restrict__ O, int n) {
    int w = (blockIdx.x * 256 + threadIdx.x) >> 6;
    int lane = threadIdx.x & 63;
    if (w >= n) return;
    unsigned self = X[(size_t)w * 64 + lane];
    float a0x = bf2f(self & 0xffff), a0y = bf2f(self >> 16);
    float a1x = 0.f, a1y = 0.f, a2x = 0.f, a2y = 0.f, a3x = 0.f, a3y = 0.f;
    int st = off[w], c = cnt[w];
    int e = 0;
    for (; e + 4 <= c; e += 4) {
        int s0 = csr[st + e], s1 = csr[st + e + 1], s2 = csr[st + e + 2], s3 = csr[st + e + 3];
        unsigned u0 = X[(size_t)s0 * 64 + lane];
        unsigned u1 = X[(size_t)s1 * 64 + lane];
        unsigned u2 = X[(size_t)s2 * 64 + lane];
        unsigned u3 = X[(size_t)s3 * 64 + lane];
        a0x += bf2f(u0 & 0xffff); a0y += bf2f(u0 >> 16);
        a1x += bf2f(u1 & 0xffff); a1y += bf2f(u1 >> 16);
        a2x += bf2f(u2 & 0xffff); a2y += bf2f(u2 >> 16);
        a3x += bf2f(u3 & 0xffff); a3y += bf2f(u3 >> 16);
    }
    for (; e < c; ++e) {
        int s = csr[st + e];
        unsigned u = X[(size_t)s * 64 + lane];
        a0x += bf2f(u & 0xffff); a0y += bf2f(u >> 16);
    }
    float di = dinv[w];
    float ox = di * (a0x + a1x + a2x + a3x);
    float oy = di * (a0y + a1y + a2y + a3y);
    O[(size_t)w * 64 + lane] = (unsigned)f2bf(ox) | ((unsigned)f2bf(oy) << 16);
}

__global__ __launch_bounds__(256) void agg256_k(const uint2* __restrict__ H,
                                                const int* __restrict__ csr,
                                                const int* __restrict__ off,
                                                const int* __restrict__ cnt,
                                                const float* __restrict__ dinv,
                                                uint2* __restrict__ O, int n) {
    int w = (blockIdx.x * 256 + threadIdx.x) >> 6;
    int lane = threadIdx.x & 63;
    if (w >= n) return;
    uint2 self = H[(size_t)w * 64 + lane];
    float a0 = bf2f(self.x & 0xffff), a1 = bf2f(self.x >> 16);
    float a2 = bf2f(self.y & 0xffff), a3 = bf2f(self.y >> 16);
    float b0 = 0.f, b1 = 0.f, b2 = 0.f, b3 = 0.f;
    float c0 = 0.f, c1 = 0.f, c2 = 0.f, c3 = 0.f;
    float d0 = 0.f, d1 = 0.f, d2 = 0.f, d3 = 0.f;
    int st = off[w], c = cnt[w];
    int e = 0;
    for (; e + 4 <= c; e += 4) {
        int s0 = csr[st + e], s1 = csr[st + e + 1], s2 = csr[st + e + 2], s3 = csr[st + e + 3];
        uint2 r0 = H[(size_t)s0 * 64 + lane];
        uint2 r1 = H[(size_t)s1 * 64 + lane];
        uint2 r2 = H[(size_t)s2 * 64 + lane];
        uint2 r3 = H[(size_t)s3 * 64 + lane];
        a0 += bf2f(r0.x & 0xffff); a1 += bf2f(r0.x >> 16); a2 += bf2f(r0.y & 0xffff); a3 += bf2f(r0.y >> 16);
        b0 += bf2f(r1.x & 0xffff); b1 += bf2f(r1.x >> 16); b2 += bf2f(r1.y & 0xffff); b3 += bf2f(r1.y >> 16);
        c0 += bf2f(r2.x & 0xffff); c1 += bf2f(r2.x >> 16); c2 += bf2f(r2.y & 0xffff); c3 += bf2f(r2.y >> 16);
        d0 += bf2f(r3.x & 0xffff); d1 += bf2f(r3.x >> 16); d2 += bf2f(r3.y & 0xffff); d3 += bf2f(r3.y >> 16);
    }
    for (; e < c; ++e) {
        int s = csr[st + e];
        uint2 r = H[(size_t)s * 64 + lane];
        a0 += bf2f(r.x & 0xffff); a1 += bf2f(r.x >> 16);
        a2 += bf2f(r.y & 0xffff); a3 += bf2f(r.y >> 16);
    }
    float di = dinv[w];
    float o0 = di * (a0 + b0 + c0 + d0);
    float o1 = di * (a1 + b1 + c1 + d1);
    float o2 = di * (a2 + b2 + c2 + d2);
    float o3 = di * (a3 + b3 + c3 + d3);
    uint2 o;
    o.x = (unsigned)f2bf(o0) | ((unsigned)f2bf(o1) << 16);
    o.y = (unsigned)f2bf(o2) | ((unsigned)f2bf(o3) << 16);
    O[(size_t)w * 64 + lane] = o;
}

// ------------------------- MFMA bf16 GEMM -----------------------------------
template <int MODE>
__global__ __launch_bounds__(256) void mgemm_k(const unsigned short* __restrict__ A,
                                               const unsigned short* __restrict__ Bt,
                                               const float* __restrict__ bias,
                                               const float* __restrict__ dinv,
                                               unsigned short* __restrict__ Hout,
                                               float* __restrict__ pool,
                                               int M, int K) {
    __shared__ __align__(16) short As[64 * 40];
    __shared__ __align__(16) short Bs[64 * 40];
    int tid = threadIdx.x;
    int w = tid >> 6, lane = tid & 63, lr = lane >> 4, lc = lane & 15;
    int row0 = blockIdx.x * 64, col0 = blockIdx.y * 64;
    int srow = tid >> 2, skoff = (tid & 3) * 8;
    f32x4 acc[4] = {};

    for (int kt = 0; kt < K; kt += 32) {
        short8 va = {};
        int gr = row0 + srow;
        if (gr < M) va = *(const short8*)(A + (size_t)gr * K + kt + skoff);
        *(short8*)&As[srow * 40 + skoff] = va;
        short8 vb = *(const short8*)(Bt + (size_t)(col0 + srow) * K + kt + skoff);
        *(short8*)&Bs[srow * 40 + skoff] = vb;
        __syncthreads();
        short8 af = *(const short8*)&As[(w * 16 + lc) * 40 + lr * 8];
#pragma unroll
        for (int f = 0; f < 4; ++f) {
            short8 bf = *(const short8*)&Bs[(f * 16 + lc) * 40 + lr * 8];
            acc[f] = __builtin_amdgcn_mfma_f32_16x16x32_bf16(af, bf, acc[f], 0, 0, 0);
        }
        __syncthreads();
    }

    float bv[4];
#pragma unroll
    for (int f = 0; f < 4; ++f) bv[f] = bias[col0 + f * 16 + lc];

    if (MODE == 1) {
#pragma unroll
        for (int r = 0; r < 4; ++r) {
            int gr = row0 + w * 16 + lr * 4 + r;
            if (gr < M) {
                float dr = dinv[gr];
#pragma unroll
                for (int f = 0; f < 4; ++f) {
                    float v = dr * fmaxf(acc[f][r] + bv[f], 0.f);
                    Hout[(size_t)gr * 256 + col0 + f * 16 + lc] = f2bf(v);
                }
            }
        }
    } else {
        __shared__ float red[16][64];
        float s[4] = {0.f, 0.f, 0.f, 0.f};
#pragma unroll
        for (int r = 0; r < 4; ++r) {
            int gr = row0 + w * 16 + lr * 4 + r;
            if (gr < M) {
#pragma unroll
                for (int f = 0; f < 4; ++f)
                    s[f] += fmaxf(acc[f][r] + bv[f], 0.f);
            }
        }
#pragma unroll
        for (int f = 0; f < 4; ++f) red[w * 4 + lr][f * 16 + lc] = s[f];
        __syncthreads();
        if (tid < 64) {
            float t = 0.f;
#pragma unroll
            for (int rr = 0; rr < 16; ++rr) t += red[rr][tid];
            atomicAdd(&pool[col0 + tid], t);
        }
    }
}

__global__ void final_k(const float* __restrict__ pool, const float* __restrict__ Wout,
                        const float* __restrict__ bout, float* __restrict__ out, float invM) {
    __shared__ float s[256];
    int t = threadIdx.x;
    s[t] = pool[t] * invM * Wout[t];
    __syncthreads();
    for (int o = 128; o > 0; o >>= 1) {
        if (t < o) s[t] += s[t + o];
        __syncthreads();
    }
    if (t == 0) out[0] = s[0] + bout[0];
}

extern "C" void kernel_launch(void* const* d_in, const int* in_sizes, int n_in,
                              void* d_out, int out_size, void* d_ws, size_t ws_size,
                              hipStream_t stream) {
    const float* x    = (const float*)d_in[0];
    const int*   ei   = (const int*)d_in[1];
    const float* W1   = (const float*)d_in[2];
    const float* b1   = (const float*)d_in[3];
    const float* W2   = (const float*)d_in[4];
    const float* b2   = (const float*)d_in[5];
    const float* Wout = (const float*)d_in[6];
    const float* bout = (const float*)d_in[7];
    float* out = (float*)d_out;

    const int N = in_sizes[0] / 128;       // 100000
    const int E = in_sizes[1] / 2;         // 1600000
    const int nb = (N + 255) / 256;
    const int NB = (N + BKT_NODES - 1) / BKT_NODES;   // buckets

    char* p = (char*)d_ws;
    auto carve = [&](size_t bytes) -> void* {
        void* r = (void*)p;
        p += (bytes + 511) & ~(size_t)511;
        return r;
    };
    unsigned*       Xs   = (unsigned*)carve((size_t)N * 128 * 2);
    unsigned*       Xp   = (unsigned*)carve((size_t)N * 128 * 2);
    unsigned short* H1   = (unsigned short*)carve((size_t)N * 256 * 2);
    unsigned short* G    = (unsigned short*)carve((size_t)N * 256 * 2);
    unsigned short* Wt1  = (unsigned short*)carve((size_t)128 * 256 * 2);
    unsigned short* Wt2  = (unsigned short*)carve((size_t)256 * 256 * 2);
    float* dinv   = (float*)carve((size_t)N * 4);
    int*   cnt    = (int*)carve((size_t)N * 4);
    int*   off    = (int*)carve((size_t)(N + 1) * 4);
    int*   csr    = (int*)carve((size_t)E * 4);
    uint2* pairs  = (uint2*)carve((size_t)E * 8);
    int*   bcur   = (int*)carve((size_t)NB * 4);
    int*   bsum   = (int*)carve((size_t)nb * 4);
    int*   bscan  = (int*)carve((size_t)nb * 4);
    float* pool   = (float*)carve(256 * 4);

    hipMemsetAsync(cnt, 0, (size_t)N * 4, stream);
    hipMemsetAsync(pool, 0, 256 * 4, stream);

    count_k<<<(E + 255) / 256, 256, 0, stream>>>(ei, cnt, E, N);
    dinv_k<<<(N + 255) / 256, 256, 0, stream>>>(cnt, dinv, N);
    cvtx_k<<<(N * 64 + 255) / 256, 256, 0, stream>>>(x, dinv, Xs, N * 64);
    wt_k<<<(128 * 256 + 255) / 256, 256, 0, stream>>>(W1, Wt1, 128);
    wt_k<<<(256 * 256 + 255) / 256, 256, 0, stream>>>(W2, Wt2, 256);
    block_sum_k<<<nb, 256, 0, stream>>>(cnt, bsum, N);
    scan_bsums_k<<<1, 512, 0, stream>>>(bsum, bscan, nb);
    scan_final_k<<<nb, 256, 0, stream>>>(cnt, bscan, off, N);
    bcur_k<<<(NB + 255) / 256, 256, 0, stream>>>(off, bcur, NB);
    bin_k<<<(E + BIN_CHUNK - 1) / BIN_CHUNK, 256, 0, stream>>>(ei, bcur, pairs, E, N, NB);
    scatter_k<<<NB, 256, 0, stream>>>(pairs, off, csr, N);

    // layer 1
    agg128_k<<<(N + 3) / 4, 256, 0, stream>>>(Xs, csr, off, cnt, dinv, Xp, N);
    mgemm_k<1><<<dim3((N + 63) / 64, 4), 256, 0, stream>>>(
        (const unsigned short*)Xp, Wt1, b1, dinv, H1, nullptr, N, 128);

    // layer 2
    agg256_k<<<(N + 3) / 4, 256, 0, stream>>>((const uint2*)H1, csr, off, cnt, dinv, (uint2*)G, N);
    mgemm_k<2><<<dim3((N + 63) / 64, 4), 256, 0, stream>>>(
        G, Wt2, b2, nullptr, nullptr, pool, N, 256);

    final_k<<<1, 256, 0, stream>>>(pool, Wout, bout, out, 1.0f / N);
}

// Round 6
// 415.073 us; speedup vs baseline: 3.0815x; 1.1235x over previous
//
#include <hip/hip_runtime.h>
#include <hip/hip_bf16.h>

// ---------------------------------------------------------------------------
// GCN forward, reassociated, bf16 data path:
//   Xs = (dinv .* x)              bf16  [N,128]
//   X' = dinv .* (Xs_self + sum_e Xs[src])   (agg128, unroll8) bf16 [N,128]
//   h1' = dinv .* relu(X'@W1 + b1)           (MFMA GEMM1)      bf16 [N,256]
//   g  = dinv .* (h1'_self + sum_e h1'[src]) (agg256, unroll8) bf16 [N,256]
//   pool = colsum(relu(g@W2 + b2))           (MFMA GEMM2, fused, no h2)
//   out = (pool/N)@Wout + bout
// CSR build: count -> scan -> bucketed two-pass fill (bin_k + scatter_k).
// GEMM: 64 rows x 256 cols per block (A streamed exactly once).
// ---------------------------------------------------------------------------

typedef __attribute__((ext_vector_type(8))) short short8;
typedef __attribute__((ext_vector_type(4))) float f32x4;

#define BKT_SHIFT 9
#define BKT_NODES 512
#define BIN_CHUNK 8192

__device__ inline float bf2f(unsigned short u) {
    union { unsigned u; float f; } v; v.u = (unsigned)u << 16; return v.f;
}
__device__ inline unsigned short f2bf(float f) {
    union { float f; unsigned u; } v; v.f = f;
    unsigned r = (v.u + 0x7fff + ((v.u >> 16) & 1)) >> 16;
    return (unsigned short)r;
}

// ----------------------------- CSR build ------------------------------------
__global__ void count_k(const int* __restrict__ ei, int* __restrict__ cnt, int E, int N) {
    int e = blockIdx.x * blockDim.x + threadIdx.x;
    if (e < E) {
        unsigned d = (unsigned)ei[(size_t)E + e];
        if (d < (unsigned)N) atomicAdd(&cnt[d], 1);
    }
}

__global__ void dinv_k(const int* __restrict__ cnt, float* __restrict__ dinv, int n) {
    int i = blockIdx.x * blockDim.x + threadIdx.x;
    if (i < n) dinv[i] = rsqrtf((float)cnt[i] + 1.0f);
}

__global__ void block_sum_k(const int* __restrict__ cnt, int* __restrict__ bsum, int n) {
    __shared__ int s[256];
    int t = threadIdx.x;
    int idx = blockIdx.x * 256 + t;
    s[t] = (idx < n) ? cnt[idx] : 0;
    __syncthreads();
    for (int o = 128; o > 0; o >>= 1) {
        if (t < o) s[t] += s[t + o];
        __syncthreads();
    }
    if (t == 0) bsum[blockIdx.x] = s[0];
}

__global__ void scan_bsums_k(const int* __restrict__ bsum, int* __restrict__ bscan, int nb) {
    __shared__ int s[2][512];
    int t = threadIdx.x;
    int v = (t < nb) ? bsum[t] : 0;
    s[0][t] = v;
    __syncthreads();
    int cur = 0;
    for (int o = 1; o < 512; o <<= 1) {
        int val = s[cur][t];
        if (t >= o) val += s[cur][t - o];
        s[cur ^ 1][t] = val;
        cur ^= 1;
        __syncthreads();
    }
    if (t < nb) bscan[t] = s[cur][t] - v;  // exclusive
}

__global__ void scan_final_k(const int* __restrict__ cnt, const int* __restrict__ bscan,
                             int* __restrict__ off, int n) {
    __shared__ int s[2][256];
    int t = threadIdx.x;
    int idx = blockIdx.x * 256 + t;
    int v = (idx < n) ? cnt[idx] : 0;
    s[0][t] = v;
    __syncthreads();
    int cur = 0;
    for (int o = 1; o < 256; o <<= 1) {
        int val = s[cur][t];
        if (t >= o) val += s[cur][t - o];
        s[cur ^ 1][t] = val;
        cur ^= 1;
        __syncthreads();
    }
    int ex = s[cur][t] - v + bscan[blockIdx.x];
    if (idx < n) {
        off[idx] = ex;
        if (idx == n - 1) off[n] = ex + v;   // total valid edges
    }
}

__global__ void bcur_k(const int* __restrict__ off, int* __restrict__ bcur, int NB) {
    int b = blockIdx.x * 256 + threadIdx.x;
    if (b < NB) bcur[b] = off[b << BKT_SHIFT];
}

// pass 1: bucket-binned pair staging. One block per 8192-edge chunk.
__global__ __launch_bounds__(256) void bin_k(const int* __restrict__ ei,
                                             int* __restrict__ bcur,
                                             uint2* __restrict__ pairs,
                                             int E, int N, int NB) {
    __shared__ int hist[256];
    __shared__ int base[256];
    int chunk0 = blockIdx.x * BIN_CHUNK;
    for (int t = threadIdx.x; t < NB; t += 256) hist[t] = 0;
    __syncthreads();
#pragma unroll 4
    for (int i = 0; i < BIN_CHUNK / 256; ++i) {
        int e = chunk0 + i * 256 + threadIdx.x;
        if (e < E) {
            unsigned d = (unsigned)ei[(size_t)E + e];
            if (d < (unsigned)N) atomicAdd(&hist[d >> BKT_SHIFT], 1);
        }
    }
    __syncthreads();
    for (int t = threadIdx.x; t < NB; t += 256) {
        int c = hist[t];
        base[t] = c ? atomicAdd(&bcur[t], c) : 0;
        hist[t] = 0;
    }
    __syncthreads();
#pragma unroll 4
    for (int i = 0; i < BIN_CHUNK / 256; ++i) {
        int e = chunk0 + i * 256 + threadIdx.x;
        if (e < E) {
            unsigned d = (unsigned)ei[(size_t)E + e];
            unsigned s = (unsigned)ei[e];
            if (d < (unsigned)N && s < (unsigned)N) {
                int b = d >> BKT_SHIFT;
                int r = atomicAdd(&hist[b], 1);
                pairs[base[b] + r] = make_uint2(s, d);
            }
        }
    }
}

// pass 2: one block per bucket; LDS per-node cursors; localized csr writes.
__global__ __launch_bounds__(256) void scatter_k(const uint2* __restrict__ pairs,
                                                 const int* __restrict__ off,
                                                 int* __restrict__ csr, int N) {
    __shared__ int cur[BKT_NODES];
    int b = blockIdx.x;
    int lo = b << BKT_SHIFT;
    int hi = min(lo + BKT_NODES, N);
    for (int t = threadIdx.x; t < hi - lo; t += 256) cur[t] = off[lo + t];
    __syncthreads();
    int rs = off[lo], re = off[hi];
    for (int i = rs + threadIdx.x; i < re; i += 256) {
        uint2 p = pairs[i];
        int pos = atomicAdd(&cur[p.y - lo], 1);
        csr[pos] = (int)p.x;
    }
}

// ----------------------------- conversions ----------------------------------
__global__ void cvtx_k(const float* __restrict__ x, const float* __restrict__ dinv,
                       unsigned* __restrict__ Xs, int n64) {
    int idx = blockIdx.x * 256 + threadIdx.x;
    if (idx >= n64) return;
    int i = idx >> 6;
    float2 v = ((const float2*)x)[idx];
    float di = dinv[i];
    Xs[idx] = (unsigned)f2bf(di * v.x) | ((unsigned)f2bf(di * v.y) << 16);
}

__global__ void wt_k(const float* __restrict__ W, unsigned short* __restrict__ Wt, int K) {
    int idx = blockIdx.x * 256 + threadIdx.x;
    if (idx >= K * 256) return;
    int k = idx >> 8, nn = idx & 255;
    Wt[nn * K + k] = f2bf(W[idx]);
}

// --------------------- aggregation (one wave per node, unroll 8) ------------
__global__ __launch_bounds__(256) void agg128_k(const unsigned* __restrict__ X,
                                                const int* __restrict__ csr,
                                                const int* __restrict__ off,
                                                const float* __restrict__ dinv,
                                                unsigned* __restrict__ O, int n) {
    int w = (blockIdx.x * 256 + threadIdx.x) >> 6;
    int lane = threadIdx.x & 63;
    if (w >= n) return;
    int st = off[w], c = off[w + 1] - st;
    float di = dinv[w];
    unsigned self = X[(size_t)w * 64 + lane];
    float ax[4], ay[4];
    ax[0] = bf2f(self & 0xffff); ay[0] = bf2f(self >> 16);
    ax[1] = ax[2] = ax[3] = 0.f; ay[1] = ay[2] = ay[3] = 0.f;
    int e = 0;
    for (; e + 8 <= c; e += 8) {
        int s[8];
#pragma unroll
        for (int j = 0; j < 8; ++j) s[j] = csr[st + e + j];
        unsigned u[8];
#pragma unroll
        for (int j = 0; j < 8; ++j) u[j] = X[(size_t)s[j] * 64 + lane];
#pragma unroll
        for (int j = 0; j < 8; ++j) {
            ax[j & 3] += bf2f(u[j] & 0xffff);
            ay[j & 3] += bf2f(u[j] >> 16);
        }
    }
    if (e + 4 <= c) {
        int s[4];
#pragma unroll
        for (int j = 0; j < 4; ++j) s[j] = csr[st + e + j];
        unsigned u[4];
#pragma unroll
        for (int j = 0; j < 4; ++j) u[j] = X[(size_t)s[j] * 64 + lane];
#pragma unroll
        for (int j = 0; j < 4; ++j) {
            ax[j] += bf2f(u[j] & 0xffff);
            ay[j] += bf2f(u[j] >> 16);
        }
        e += 4;
    }
    for (; e < c; ++e) {
        int s = csr[st + e];
        unsigned u = X[(size_t)s * 64 + lane];
        ax[0] += bf2f(u & 0xffff); ay[0] += bf2f(u >> 16);
    }
    float ox = di * ((ax[0] + ax[1]) + (ax[2] + ax[3]));
    float oy = di * ((ay[0] + ay[1]) + (ay[2] + ay[3]));
    O[(size_t)w * 64 + lane] = (unsigned)f2bf(ox) | ((unsigned)f2bf(oy) << 16);
}

__global__ __launch_bounds__(256) void agg256_k(const uint2* __restrict__ H,
                                                const int* __restrict__ csr,
                                                const int* __restrict__ off,
                                                const float* __restrict__ dinv,
                                                uint2* __restrict__ O, int n) {
    int w = (blockIdx.x * 256 + threadIdx.x) >> 6;
    int lane = threadIdx.x & 63;
    if (w >= n) return;
    int st = off[w], c = off[w + 1] - st;
    float di = dinv[w];
    uint2 self = H[(size_t)w * 64 + lane];
    float a[4][4];
    a[0][0] = bf2f(self.x & 0xffff); a[0][1] = bf2f(self.x >> 16);
    a[0][2] = bf2f(self.y & 0xffff); a[0][3] = bf2f(self.y >> 16);
#pragma unroll
    for (int g = 1; g < 4; ++g) { a[g][0] = a[g][1] = a[g][2] = a[g][3] = 0.f; }
    int e = 0;
    for (; e + 8 <= c; e += 8) {
        int s[8];
#pragma unroll
        for (int j = 0; j < 8; ++j) s[j] = csr[st + e + j];
        uint2 u[8];
#pragma unroll
        for (int j = 0; j < 8; ++j) u[j] = H[(size_t)s[j] * 64 + lane];
#pragma unroll
        for (int j = 0; j < 8; ++j) {
            a[j & 3][0] += bf2f(u[j].x & 0xffff);
            a[j & 3][1] += bf2f(u[j].x >> 16);
            a[j & 3][2] += bf2f(u[j].y & 0xffff);
            a[j & 3][3] += bf2f(u[j].y >> 16);
        }
    }
    if (e + 4 <= c) {
        int s[4];
#pragma unroll
        for (int j = 0; j < 4; ++j) s[j] = csr[st + e + j];
        uint2 u[4];
#pragma unroll
        for (int j = 0; j < 4; ++j) u[j] = H[(size_t)s[j] * 64 + lane];
#pragma unroll
        for (int j = 0; j < 4; ++j) {
            a[j][0] += bf2f(u[j].x & 0xffff);
            a[j][1] += bf2f(u[j].x >> 16);
            a[j][2] += bf2f(u[j].y & 0xffff);
            a[j][3] += bf2f(u[j].y >> 16);
        }
        e += 4;
    }
    for (; e < c; ++e) {
        int s = csr[st + e];
        uint2 u = H[(size_t)s * 64 + lane];
        a[0][0] += bf2f(u.x & 0xffff); a[0][1] += bf2f(u.x >> 16);
        a[0][2] += bf2f(u.y & 0xffff); a[0][3] += bf2f(u.y >> 16);
    }
    float o0 = di * ((a[0][0] + a[1][0]) + (a[2][0] + a[3][0]));
    float o1 = di * ((a[0][1] + a[1][1]) + (a[2][1] + a[3][1]));
    float o2 = di * ((a[0][2] + a[1][2]) + (a[2][2] + a[3][2]));
    float o3 = di * ((a[0][3] + a[1][3]) + (a[2][3] + a[3][3]));
    uint2 o;
    o.x = (unsigned)f2bf(o0) | ((unsigned)f2bf(o1) << 16);
    o.y = (unsigned)f2bf(o2) | ((unsigned)f2bf(o3) << 16);
    O[(size_t)w * 64 + lane] = o;
}

// ------------------------- MFMA bf16 GEMM -----------------------------------
// C[M,256] = A[M,K](bf16) @ Bt[256,K](bf16)^T ; 64 rows x 256 cols per block,
// 4 waves, K_STEP=32. A is streamed exactly once (no col-tile re-reads).
// MODE 1: Hout[r][c] = bf16( dinv[r]*relu(acc+bias[c]) )
// MODE 2: pool[c] += sum_r relu(acc+bias[c])   (no Hout)
template <int MODE>
__global__ __launch_bounds__(256) void mgemm_k(const unsigned short* __restrict__ A,
                                               const unsigned short* __restrict__ Bt,
                                               const float* __restrict__ bias,
                                               const float* __restrict__ dinv,
                                               unsigned short* __restrict__ Hout,
                                               float* __restrict__ pool,
                                               int M, int K) {
    __shared__ __align__(16) short As[64 * 40];    // 64 rows x 32k (+8 pad)
    __shared__ __align__(16) short Bs[256 * 40];   // 256 cols x 32k (+8 pad)
    int tid = threadIdx.x;
    int w = tid >> 6, lane = tid & 63, lr = lane >> 4, lc = lane & 15;
    int row0 = blockIdx.x * 64;
    int arow = tid >> 2, akoff = (tid & 3) * 8;
    f32x4 acc[16] = {};

    for (int kt = 0; kt < K; kt += 32) {
        short8 va = {};
        int gr = row0 + arow;
        if (gr < M) va = *(const short8*)(A + (size_t)gr * K + kt + akoff);
        *(short8*)&As[arow * 40 + akoff] = va;
#pragma unroll
        for (int l = 0; l < 4; ++l) {
            int f = tid + l * 256;          // 1024 short8 slots: 256 rows x 4
            int br = f >> 2, bk = (f & 3) * 8;
            short8 vb = *(const short8*)(Bt + (size_t)br * K + kt + bk);
            *(short8*)&Bs[br * 40 + bk] = vb;
        }
        __syncthreads();
        short8 af = *(const short8*)&As[(w * 16 + lc) * 40 + lr * 8];
#pragma unroll
        for (int f = 0; f < 16; ++f) {
            short8 bf = *(const short8*)&Bs[(f * 16 + lc) * 40 + lr * 8];
            acc[f] = __builtin_amdgcn_mfma_f32_16x16x32_bf16(af, bf, acc[f], 0, 0, 0);
        }
        __syncthreads();
    }

    float bv[16];
#pragma unroll
    for (int f = 0; f < 16; ++f) bv[f] = bias[f * 16 + lc];

    if (MODE == 1) {
#pragma unroll
        for (int r = 0; r < 4; ++r) {
            int gr = row0 + w * 16 + lr * 4 + r;
            if (gr < M) {
                float dr = dinv[gr];
#pragma unroll
                for (int f = 0; f < 16; ++f) {
                    float v = dr * fmaxf(acc[f][r] + bv[f], 0.f);
                    Hout[(size_t)gr * 256 + f * 16 + lc] = f2bf(v);
                }
            }
        }
    } else {
        __shared__ float red[16][256];
        float s[16];
#pragma unroll
        for (int f = 0; f < 16; ++f) s[f] = 0.f;
#pragma unroll
        for (int r = 0; r < 4; ++r) {
            int gr = row0 + w * 16 + lr * 4 + r;
            if (gr < M) {
#pragma unroll
                for (int f = 0; f < 16; ++f)
                    s[f] += fmaxf(acc[f][r] + bv[f], 0.f);
            }
        }
#pragma unroll
        for (int f = 0; f < 16; ++f) red[w * 4 + lr][f * 16 + lc] = s[f];
        __syncthreads();
        float t = 0.f;
#pragma unroll
        for (int rr = 0; rr < 16; ++rr) t += red[rr][tid];
        atomicAdd(&pool[tid], t);
    }
}

__global__ void final_k(const float* __restrict__ pool, const float* __restrict__ Wout,
                        const float* __restrict__ bout, float* __restrict__ out, float invM) {
    __shared__ float s[256];
    int t = threadIdx.x;
    s[t] = pool[t] * invM * Wout[t];
    __syncthreads();
    for (int o = 128; o > 0; o >>= 1) {
        if (t < o) s[t] += s[t + o];
        __syncthreads();
    }
    if (t == 0) out[0] = s[0] + bout[0];
}

extern "C" void kernel_launch(void* const* d_in, const int* in_sizes, int n_in,
                              void* d_out, int out_size, void* d_ws, size_t ws_size,
                              hipStream_t stream) {
    const float* x    = (const float*)d_in[0];
    const int*   ei   = (const int*)d_in[1];
    const float* W1   = (const float*)d_in[2];
    const float* b1   = (const float*)d_in[3];
    const float* W2   = (const float*)d_in[4];
    const float* b2   = (const float*)d_in[5];
    const float* Wout = (const float*)d_in[6];
    const float* bout = (const float*)d_in[7];
    float* out = (float*)d_out;

    const int N = in_sizes[0] / 128;       // 100000
    const int E = in_sizes[1] / 2;         // 1600000
    const int nb = (N + 255) / 256;
    const int NB = (N + BKT_NODES - 1) / BKT_NODES;

    char* p = (char*)d_ws;
    auto carve = [&](size_t bytes) -> void* {
        void* r = (void*)p;
        p += (bytes + 511) & ~(size_t)511;
        return r;
    };
    unsigned*       Xs   = (unsigned*)carve((size_t)N * 128 * 2);
    unsigned*       Xp   = (unsigned*)carve((size_t)N * 128 * 2);
    unsigned short* H1   = (unsigned short*)carve((size_t)N * 256 * 2);
    unsigned short* G    = (unsigned short*)carve((size_t)N * 256 * 2);
    unsigned short* Wt1  = (unsigned short*)carve((size_t)128 * 256 * 2);
    unsigned short* Wt2  = (unsigned short*)carve((size_t)256 * 256 * 2);
    float* dinv   = (float*)carve((size_t)N * 4);
    int*   cnt    = (int*)carve((size_t)N * 4);
    int*   off    = (int*)carve((size_t)(N + 1) * 4);
    int*   csr    = (int*)carve((size_t)E * 4);
    uint2* pairs  = (uint2*)carve((size_t)E * 8);
    int*   bcur   = (int*)carve((size_t)NB * 4);
    int*   bsum   = (int*)carve((size_t)nb * 4);
    int*   bscan  = (int*)carve((size_t)nb * 4);
    float* pool   = (float*)carve(256 * 4);

    hipMemsetAsync(cnt, 0, (size_t)N * 4, stream);
    hipMemsetAsync(pool, 0, 256 * 4, stream);

    count_k<<<(E + 255) / 256, 256, 0, stream>>>(ei, cnt, E, N);
    dinv_k<<<(N + 255) / 256, 256, 0, stream>>>(cnt, dinv, N);
    cvtx_k<<<(N * 64 + 255) / 256, 256, 0, stream>>>(x, dinv, Xs, N * 64);
    wt_k<<<(128 * 256 + 255) / 256, 256, 0, stream>>>(W1, Wt1, 128);
    wt_k<<<(256 * 256 + 255) / 256, 256, 0, stream>>>(W2, Wt2, 256);
    block_sum_k<<<nb, 256, 0, stream>>>(cnt, bsum, N);
    scan_bsums_k<<<1, 512, 0, stream>>>(bsum, bscan, nb);
    scan_final_k<<<nb, 256, 0, stream>>>(cnt, bscan, off, N);
    bcur_k<<<(NB + 255) / 256, 256, 0, stream>>>(off, bcur, NB);
    bin_k<<<(E + BIN_CHUNK - 1) / BIN_CHUNK, 256, 0, stream>>>(ei, bcur, pairs, E, N, NB);
    scatter_k<<<NB, 256, 0, stream>>>(pairs, off, csr, N);

    // layer 1
    agg128_k<<<(N + 3) / 4, 256, 0, stream>>>(Xs, csr, off, dinv, Xp, N);
    mgemm_k<1><<<(N + 63) / 64, 256, 0, stream>>>(
        (const unsigned short*)Xp, Wt1, b1, dinv, H1, nullptr, N, 128);

    // layer 2
    agg256_k<<<(N + 3) / 4, 256, 0, stream>>>((const uint2*)H1, csr, off, dinv, (uint2*)G, N);
    mgemm_k<2><<<(N + 63) / 64, 256, 0, stream>>>(
        G, Wt2, b2, nullptr, nullptr, pool, N, 256);

    final_k<<<1, 256, 0, stream>>>(pool, Wout, bout, out, 1.0f / N);
}

// Round 7
// 348.072 us; speedup vs baseline: 3.6747x; 1.1925x over previous
//
#include <hip/hip_runtime.h>
#include <hip/hip_bf16.h>

// ---------------------------------------------------------------------------
// GCN forward, reassociated; fp8(e4m3) gather payloads, bf16 MFMA, fp32 accum:
//   Xs  = fp8(dinv .* x)                         [N,128] fp8 (12.8 MB)
//   X'  = bf16( dinv .* (Xs_self + sum Xs[src]) )  (agg128)   [N,128] bf16
//   H1  = fp8( dinv .* relu(X'@W1 + b1) )          (MFMA GEMM1 epilogue) [N,256] fp8
//   g   = bf16( dinv .* (H1_self + sum H1[src]) )  (agg256)   [N,256] bf16
//   pool = colsum(relu(g@W2 + b2))                 (MFMA GEMM2, fused)
//   out = (pool/N)@Wout + bout
// Gather is traffic-bound beyond L2 (r6: 2x MLP -> 0 delta); fp8 halves bytes.
// CSR build: count -> scan -> bucketed two-pass fill (bin_k + scatter_k).
// ---------------------------------------------------------------------------

typedef __attribute__((ext_vector_type(8))) short short8;
typedef __attribute__((ext_vector_type(4))) float f32x4;
typedef __attribute__((ext_vector_type(2))) float f32x2;

#define BKT_SHIFT 9
#define BKT_NODES 512
#define BIN_CHUNK 8192

__device__ inline float bf2f(unsigned short u) {
    union { unsigned u; float f; } v; v.u = (unsigned)u << 16; return v.f;
}
__device__ inline unsigned short f2bf(float f) {
    union { float f; unsigned u; } v; v.f = f;
    unsigned r = (v.u + 0x7fff + ((v.u >> 16) & 1)) >> 16;
    return (unsigned short)r;
}
__device__ inline unsigned char f2fp8(float v) {
    v = fminf(fmaxf(v, -448.f), 448.f);
    int p = __builtin_amdgcn_cvt_pk_fp8_f32(v, v, 0, false);
    return (unsigned char)(p & 0xff);
}

// ----------------------------- CSR build ------------------------------------
__global__ void count_k(const int* __restrict__ ei, int* __restrict__ cnt, int E, int N) {
    int e = blockIdx.x * blockDim.x + threadIdx.x;
    if (e < E) {
        unsigned d = (unsigned)ei[(size_t)E + e];
        if (d < (unsigned)N) atomicAdd(&cnt[d], 1);
    }
}

__global__ void dinv_k(const int* __restrict__ cnt, float* __restrict__ dinv, int n) {
    int i = blockIdx.x * blockDim.x + threadIdx.x;
    if (i < n) dinv[i] = rsqrtf((float)cnt[i] + 1.0f);
}

__global__ void block_sum_k(const int* __restrict__ cnt, int* __restrict__ bsum, int n) {
    __shared__ int s[256];
    int t = threadIdx.x;
    int idx = blockIdx.x * 256 + t;
    s[t] = (idx < n) ? cnt[idx] : 0;
    __syncthreads();
    for (int o = 128; o > 0; o >>= 1) {
        if (t < o) s[t] += s[t + o];
        __syncthreads();
    }
    if (t == 0) bsum[blockIdx.x] = s[0];
}

__global__ void scan_bsums_k(const int* __restrict__ bsum, int* __restrict__ bscan, int nb) {
    __shared__ int s[2][512];
    int t = threadIdx.x;
    int v = (t < nb) ? bsum[t] : 0;
    s[0][t] = v;
    __syncthreads();
    int cur = 0;
    for (int o = 1; o < 512; o <<= 1) {
        int val = s[cur][t];
        if (t >= o) val += s[cur][t - o];
        s[cur ^ 1][t] = val;
        cur ^= 1;
        __syncthreads();
    }
    if (t < nb) bscan[t] = s[cur][t] - v;  // exclusive
}

__global__ void scan_final_k(const int* __restrict__ cnt, const int* __restrict__ bscan,
                             int* __restrict__ off, int n) {
    __shared__ int s[2][256];
    int t = threadIdx.x;
    int idx = blockIdx.x * 256 + t;
    int v = (idx < n) ? cnt[idx] : 0;
    s[0][t] = v;
    __syncthreads();
    int cur = 0;
    for (int o = 1; o < 256; o <<= 1) {
        int val = s[cur][t];
        if (t >= o) val += s[cur][t - o];
        s[cur ^ 1][t] = val;
        cur ^= 1;
        __syncthreads();
    }
    int ex = s[cur][t] - v + bscan[blockIdx.x];
    if (idx < n) {
        off[idx] = ex;
        if (idx == n - 1) off[n] = ex + v;
    }
}

__global__ void bcur_k(const int* __restrict__ off, int* __restrict__ bcur, int NB) {
    int b = blockIdx.x * 256 + threadIdx.x;
    if (b < NB) bcur[b] = off[b << BKT_SHIFT];
}

__global__ __launch_bounds__(256) void bin_k(const int* __restrict__ ei,
                                             int* __restrict__ bcur,
                                             uint2* __restrict__ pairs,
                                             int E, int N, int NB) {
    __shared__ int hist[256];
    __shared__ int base[256];
    int chunk0 = blockIdx.x * BIN_CHUNK;
    for (int t = threadIdx.x; t < NB; t += 256) hist[t] = 0;
    __syncthreads();
#pragma unroll 4
    for (int i = 0; i < BIN_CHUNK / 256; ++i) {
        int e = chunk0 + i * 256 + threadIdx.x;
        if (e < E) {
            unsigned d = (unsigned)ei[(size_t)E + e];
            if (d < (unsigned)N) atomicAdd(&hist[d >> BKT_SHIFT], 1);
        }
    }
    __syncthreads();
    for (int t = threadIdx.x; t < NB; t += 256) {
        int c = hist[t];
        base[t] = c ? atomicAdd(&bcur[t], c) : 0;
        hist[t] = 0;
    }
    __syncthreads();
#pragma unroll 4
    for (int i = 0; i < BIN_CHUNK / 256; ++i) {
        int e = chunk0 + i * 256 + threadIdx.x;
        if (e < E) {
            unsigned d = (unsigned)ei[(size_t)E + e];
            unsigned s = (unsigned)ei[e];
            if (d < (unsigned)N && s < (unsigned)N) {
                int b = d >> BKT_SHIFT;
                int r = atomicAdd(&hist[b], 1);
                pairs[base[b] + r] = make_uint2(s, d);
            }
        }
    }
}

__global__ __launch_bounds__(256) void scatter_k(const uint2* __restrict__ pairs,
                                                 const int* __restrict__ off,
                                                 int* __restrict__ csr, int N) {
    __shared__ int cur[BKT_NODES];
    int b = blockIdx.x;
    int lo = b << BKT_SHIFT;
    int hi = min(lo + BKT_NODES, N);
    for (int t = threadIdx.x; t < hi - lo; t += 256) cur[t] = off[lo + t];
    __syncthreads();
    int rs = off[lo], re = off[hi];
    for (int i = rs + threadIdx.x; i < re; i += 256) {
        uint2 p = pairs[i];
        int pos = atomicAdd(&cur[p.y - lo], 1);
        csr[pos] = (int)p.x;
    }
}

// ----------------------------- conversions ----------------------------------
// Xs fp8[N,128]: one thread per 4 features (1 uint out)
__global__ void cvtx_k(const float* __restrict__ x, const float* __restrict__ dinv,
                       unsigned* __restrict__ Xs, int n32) {
    int idx = blockIdx.x * 256 + threadIdx.x;
    if (idx >= n32) return;
    int i = idx >> 5;
    float4 v = ((const float4*)x)[idx];
    float di = dinv[i];
    float a = fminf(fmaxf(di * v.x, -448.f), 448.f);
    float b = fminf(fmaxf(di * v.y, -448.f), 448.f);
    float c = fminf(fmaxf(di * v.z, -448.f), 448.f);
    float d = fminf(fmaxf(di * v.w, -448.f), 448.f);
    int p = __builtin_amdgcn_cvt_pk_fp8_f32(a, b, 0, false);
    p = __builtin_amdgcn_cvt_pk_fp8_f32(c, d, p, true);
    Xs[idx] = (unsigned)p;
}

__global__ void wt_k(const float* __restrict__ W, unsigned short* __restrict__ Wt, int K) {
    int idx = blockIdx.x * 256 + threadIdx.x;
    if (idx >= K * 256) return;
    int k = idx >> 8, nn = idx & 255;
    Wt[nn * K + k] = f2bf(W[idx]);
}

// --------------------- aggregation (one wave per node, unroll 8) ------------
// layer 1: fp8 rows of 128 (lane = 2 features, ushort load)
__global__ __launch_bounds__(256) void agg128_k(const unsigned short* __restrict__ X8,
                                                const int* __restrict__ csr,
                                                const int* __restrict__ off,
                                                const float* __restrict__ dinv,
                                                unsigned* __restrict__ O, int n) {
    int w = (blockIdx.x * 256 + threadIdx.x) >> 6;
    int lane = threadIdx.x & 63;
    if (w >= n) return;
    int st = off[w], c = off[w + 1] - st;
    float di = dinv[w];
    f32x2 sv = __builtin_amdgcn_cvt_pk_f32_fp8((int)X8[(size_t)w * 64 + lane], false);
    float ax[4], ay[4];
    ax[0] = sv[0]; ay[0] = sv[1];
    ax[1] = ax[2] = ax[3] = 0.f; ay[1] = ay[2] = ay[3] = 0.f;
    int e = 0;
    for (; e + 8 <= c; e += 8) {
        int s[8];
#pragma unroll
        for (int j = 0; j < 8; ++j) s[j] = csr[st + e + j];
        unsigned short u[8];
#pragma unroll
        for (int j = 0; j < 8; ++j) u[j] = X8[(size_t)s[j] * 64 + lane];
#pragma unroll
        for (int j = 0; j < 8; ++j) {
            f32x2 f = __builtin_amdgcn_cvt_pk_f32_fp8((int)u[j], false);
            ax[j & 3] += f[0]; ay[j & 3] += f[1];
        }
    }
    if (e + 4 <= c) {
        int s[4];
#pragma unroll
        for (int j = 0; j < 4; ++j) s[j] = csr[st + e + j];
        unsigned short u[4];
#pragma unroll
        for (int j = 0; j < 4; ++j) u[j] = X8[(size_t)s[j] * 64 + lane];
#pragma unroll
        for (int j = 0; j < 4; ++j) {
            f32x2 f = __builtin_amdgcn_cvt_pk_f32_fp8((int)u[j], false);
            ax[j] += f[0]; ay[j] += f[1];
        }
        e += 4;
    }
    for (; e < c; ++e) {
        int s = csr[st + e];
        f32x2 f = __builtin_amdgcn_cvt_pk_f32_fp8((int)X8[(size_t)s * 64 + lane], false);
        ax[0] += f[0]; ay[0] += f[1];
    }
    float ox = di * ((ax[0] + ax[1]) + (ax[2] + ax[3]));
    float oy = di * ((ay[0] + ay[1]) + (ay[2] + ay[3]));
    O[(size_t)w * 64 + lane] = (unsigned)f2bf(ox) | ((unsigned)f2bf(oy) << 16);
}

// layer 2: fp8 rows of 256 (lane = 4 features, uint load); out bf16 (uint2)
__global__ __launch_bounds__(256) void agg256_k(const unsigned* __restrict__ H8,
                                                const int* __restrict__ csr,
                                                const int* __restrict__ off,
                                                const float* __restrict__ dinv,
                                                uint2* __restrict__ O, int n) {
    int w = (blockIdx.x * 256 + threadIdx.x) >> 6;
    int lane = threadIdx.x & 63;
    if (w >= n) return;
    int st = off[w], c = off[w + 1] - st;
    float di = dinv[w];
    unsigned su = H8[(size_t)w * 64 + lane];
    f32x2 slo = __builtin_amdgcn_cvt_pk_f32_fp8((int)su, false);
    f32x2 shi = __builtin_amdgcn_cvt_pk_f32_fp8((int)su, true);
    float a[4][4];
    a[0][0] = slo[0]; a[0][1] = slo[1]; a[0][2] = shi[0]; a[0][3] = shi[1];
#pragma unroll
    for (int g = 1; g < 4; ++g) { a[g][0] = a[g][1] = a[g][2] = a[g][3] = 0.f; }
    int e = 0;
    for (; e + 8 <= c; e += 8) {
        int s[8];
#pragma unroll
        for (int j = 0; j < 8; ++j) s[j] = csr[st + e + j];
        unsigned u[8];
#pragma unroll
        for (int j = 0; j < 8; ++j) u[j] = H8[(size_t)s[j] * 64 + lane];
#pragma unroll
        for (int j = 0; j < 8; ++j) {
            f32x2 lo = __builtin_amdgcn_cvt_pk_f32_fp8((int)u[j], false);
            f32x2 hi = __builtin_amdgcn_cvt_pk_f32_fp8((int)u[j], true);
            a[j & 3][0] += lo[0]; a[j & 3][1] += lo[1];
            a[j & 3][2] += hi[0]; a[j & 3][3] += hi[1];
        }
    }
    if (e + 4 <= c) {
        int s[4];
#pragma unroll
        for (int j = 0; j < 4; ++j) s[j] = csr[st + e + j];
        unsigned u[4];
#pragma unroll
        for (int j = 0; j < 4; ++j) u[j] = H8[(size_t)s[j] * 64 + lane];
#pragma unroll
        for (int j = 0; j < 4; ++j) {
            f32x2 lo = __builtin_amdgcn_cvt_pk_f32_fp8((int)u[j], false);
            f32x2 hi = __builtin_amdgcn_cvt_pk_f32_fp8((int)u[j], true);
            a[j][0] += lo[0]; a[j][1] += lo[1]; a[j][2] += hi[0]; a[j][3] += hi[1];
        }
        e += 4;
    }
    for (; e < c; ++e) {
        int s = csr[st + e];
        unsigned u = H8[(size_t)s * 64 + lane];
        f32x2 lo = __builtin_amdgcn_cvt_pk_f32_fp8((int)u, false);
        f32x2 hi = __builtin_amdgcn_cvt_pk_f32_fp8((int)u, true);
        a[0][0] += lo[0]; a[0][1] += lo[1]; a[0][2] += hi[0]; a[0][3] += hi[1];
    }
    float o0 = di * ((a[0][0] + a[1][0]) + (a[2][0] + a[3][0]));
    float o1 = di * ((a[0][1] + a[1][1]) + (a[2][1] + a[3][1]));
    float o2 = di * ((a[0][2] + a[1][2]) + (a[2][2] + a[3][2]));
    float o3 = di * ((a[0][3] + a[1][3]) + (a[2][3] + a[3][3]));
    uint2 o;
    o.x = (unsigned)f2bf(o0) | ((unsigned)f2bf(o1) << 16);
    o.y = (unsigned)f2bf(o2) | ((unsigned)f2bf(o3) << 16);
    O[(size_t)w * 64 + lane] = o;
}

// ------------------------- MFMA bf16 GEMM -----------------------------------
// C[M,256] = A[M,K](bf16) @ Bt[256,K](bf16)^T ; 64 rows x 256 cols per block.
// MODE 1: Hout8[r][c] = fp8( dinv[r]*relu(acc+bias[c]) )
// MODE 2: pool[c] += sum_r relu(acc+bias[c])
template <int MODE>
__global__ __launch_bounds__(256) void mgemm_k(const unsigned short* __restrict__ A,
                                               const unsigned short* __restrict__ Bt,
                                               const float* __restrict__ bias,
                                               const float* __restrict__ dinv,
                                               unsigned char* __restrict__ Hout8,
                                               float* __restrict__ pool,
                                               int M, int K) {
    __shared__ __align__(16) short As[64 * 40];
    __shared__ __align__(16) short Bs[256 * 40];
    int tid = threadIdx.x;
    int w = tid >> 6, lane = tid & 63, lr = lane >> 4, lc = lane & 15;
    int row0 = blockIdx.x * 64;
    int arow = tid >> 2, akoff = (tid & 3) * 8;
    f32x4 acc[16] = {};

    for (int kt = 0; kt < K; kt += 32) {
        short8 va = {};
        int gr = row0 + arow;
        if (gr < M) va = *(const short8*)(A + (size_t)gr * K + kt + akoff);
        *(short8*)&As[arow * 40 + akoff] = va;
#pragma unroll
        for (int l = 0; l < 4; ++l) {
            int f = tid + l * 256;
            int br = f >> 2, bk = (f & 3) * 8;
            short8 vb = *(const short8*)(Bt + (size_t)br * K + kt + bk);
            *(short8*)&Bs[br * 40 + bk] = vb;
        }
        __syncthreads();
        short8 af = *(const short8*)&As[(w * 16 + lc) * 40 + lr * 8];
#pragma unroll
        for (int f = 0; f < 16; ++f) {
            short8 bf = *(const short8*)&Bs[(f * 16 + lc) * 40 + lr * 8];
            acc[f] = __builtin_amdgcn_mfma_f32_16x16x32_bf16(af, bf, acc[f], 0, 0, 0);
        }
        __syncthreads();
    }

    float bv[16];
#pragma unroll
    for (int f = 0; f < 16; ++f) bv[f] = bias[f * 16 + lc];

    if (MODE == 1) {
#pragma unroll
        for (int r = 0; r < 4; ++r) {
            int gr = row0 + w * 16 + lr * 4 + r;
            if (gr < M) {
                float dr = dinv[gr];
#pragma unroll
                for (int f = 0; f < 16; ++f) {
                    float v = dr * fmaxf(acc[f][r] + bv[f], 0.f);
                    Hout8[(size_t)gr * 256 + f * 16 + lc] = f2fp8(v);
                }
            }
        }
    } else {
        __shared__ float red[16][256];
        float s[16];
#pragma unroll
        for (int f = 0; f < 16; ++f) s[f] = 0.f;
#pragma unroll
        for (int r = 0; r < 4; ++r) {
            int gr = row0 + w * 16 + lr * 4 + r;
            if (gr < M) {
#pragma unroll
                for (int f = 0; f < 16; ++f)
                    s[f] += fmaxf(acc[f][r] + bv[f], 0.f);
            }
        }
#pragma unroll
        for (int f = 0; f < 16; ++f) red[w * 4 + lr][f * 16 + lc] = s[f];
        __syncthreads();
        float t = 0.f;
#pragma unroll
        for (int rr = 0; rr < 16; ++rr) t += red[rr][tid];
        atomicAdd(&pool[tid], t);
    }
}

__global__ void final_k(const float* __restrict__ pool, const float* __restrict__ Wout,
                        const float* __restrict__ bout, float* __restrict__ out, float invM) {
    __shared__ float s[256];
    int t = threadIdx.x;
    s[t] = pool[t] * invM * Wout[t];
    __syncthreads();
    for (int o = 128; o > 0; o >>= 1) {
        if (t < o) s[t] += s[t + o];
        __syncthreads();
    }
    if (t == 0) out[0] = s[0] + bout[0];
}

extern "C" void kernel_launch(void* const* d_in, const int* in_sizes, int n_in,
                              void* d_out, int out_size, void* d_ws, size_t ws_size,
                              hipStream_t stream) {
    const float* x    = (const float*)d_in[0];
    const int*   ei   = (const int*)d_in[1];
    const float* W1   = (const float*)d_in[2];
    const float* b1   = (const float*)d_in[3];
    const float* W2   = (const float*)d_in[4];
    const float* b2   = (const float*)d_in[5];
    const float* Wout = (const float*)d_in[6];
    const float* bout = (const float*)d_in[7];
    float* out = (float*)d_out;

    const int N = in_sizes[0] / 128;       // 100000
    const int E = in_sizes[1] / 2;         // 1600000
    const int nb = (N + 255) / 256;
    const int NB = (N + BKT_NODES - 1) / BKT_NODES;

    char* p = (char*)d_ws;
    auto carve = [&](size_t bytes) -> void* {
        void* r = (void*)p;
        p += (bytes + 511) & ~(size_t)511;
        return r;
    };
    unsigned*       Xs   = (unsigned*)carve((size_t)N * 128);            // fp8
    unsigned*       Xp   = (unsigned*)carve((size_t)N * 128 * 2);        // bf16
    unsigned char*  H1   = (unsigned char*)carve((size_t)N * 256);       // fp8
    unsigned short* G    = (unsigned short*)carve((size_t)N * 256 * 2);  // bf16
    unsigned short* Wt1  = (unsigned short*)carve((size_t)128 * 256 * 2);
    unsigned short* Wt2  = (unsigned short*)carve((size_t)256 * 256 * 2);
    float* dinv   = (float*)carve((size_t)N * 4);
    int*   cnt    = (int*)carve((size_t)N * 4);
    int*   off    = (int*)carve((size_t)(N + 1) * 4);
    int*   csr    = (int*)carve((size_t)E * 4);
    uint2* pairs  = (uint2*)carve((size_t)E * 8);
    int*   bcur   = (int*)carve((size_t)NB * 4);
    int*   bsum   = (int*)carve((size_t)nb * 4);
    int*   bscan  = (int*)carve((size_t)nb * 4);
    float* pool   = (float*)carve(256 * 4);

    hipMemsetAsync(cnt, 0, (size_t)N * 4, stream);
    hipMemsetAsync(pool, 0, 256 * 4, stream);

    count_k<<<(E + 255) / 256, 256, 0, stream>>>(ei, cnt, E, N);
    dinv_k<<<(N + 255) / 256, 256, 0, stream>>>(cnt, dinv, N);
    cvtx_k<<<(N * 32 + 255) / 256, 256, 0, stream>>>(x, dinv, Xs, N * 32);
    wt_k<<<(128 * 256 + 255) / 256, 256, 0, stream>>>(W1, Wt1, 128);
    wt_k<<<(256 * 256 + 255) / 256, 256, 0, stream>>>(W2, Wt2, 256);
    block_sum_k<<<nb, 256, 0, stream>>>(cnt, bsum, N);
    scan_bsums_k<<<1, 512, 0, stream>>>(bsum, bscan, nb);
    scan_final_k<<<nb, 256, 0, stream>>>(cnt, bscan, off, N);
    bcur_k<<<(NB + 255) / 256, 256, 0, stream>>>(off, bcur, NB);
    bin_k<<<(E + BIN_CHUNK - 1) / BIN_CHUNK, 256, 0, stream>>>(ei, bcur, pairs, E, N, NB);
    scatter_k<<<NB, 256, 0, stream>>>(pairs, off, csr, N);

    // layer 1
    agg128_k<<<(N + 3) / 4, 256, 0, stream>>>((const unsigned short*)Xs, csr, off, dinv, Xp, N);
    mgemm_k<1><<<(N + 63) / 64, 256, 0, stream>>>(
        (const unsigned short*)Xp, Wt1, b1, dinv, H1, nullptr, N, 128);

    // layer 2
    agg256_k<<<(N + 3) / 4, 256, 0, stream>>>((const unsigned*)H1, csr, off, dinv, (uint2*)G, N);
    mgemm_k<2><<<(N + 63) / 64, 256, 0, stream>>>(
        G, Wt2, b2, nullptr, nullptr, pool, N, 256);

    final_k<<<1, 256, 0, stream>>>(pool, Wout, bout, out, 1.0f / N);
}